// Round 7
// baseline (1515.652 us; speedup 1.0000x reference)
//
#include <hip/hip_runtime.h>

// STGAT round 7: encoder launch_bounds (512,2) -> (512,1).
// Round 6's 128-VGPR cap spilled the W-fragment registers (~90MB scratch
// writes, WRITE_SIZE 106MB). Cap 256 fits the ~180-reg live set with zero
// spill. Everything else identical to round 6 (encoder MFMA LSTMs; decoder
// round-5 known-good).

#define OBS 8
#define FUT 12
#define NPED 64
#define HT_ 32
#define HG_ 32
#define NZ_ 8
#define HP_ 72
#define NGR 1024
#define NTOT (NGR * NPED)
#define AP 104    // decoder A stride (u16)
#define EAP 72    // encoder A stride (u16): 144B rows -> 2-way bank alias (free)

typedef __attribute__((ext_vector_type(8))) short short8_t;
typedef __attribute__((ext_vector_type(4))) float f32x4;
typedef unsigned short u16;

__device__ __forceinline__ float sigf(float x) { return 1.0f / (1.0f + __expf(-x)); }
__device__ __forceinline__ float tanh_(float x) {
    float e = __expf(2.0f * x);
    return 1.0f - 2.0f / (e + 1.0f);
}
__device__ __forceinline__ float leaky(float x) { return (x > 0.0f) ? x : 0.2f * x; }
__device__ __forceinline__ u16 bhi(float v) {              // round-to-nearest-even bf16
    unsigned u = __float_as_uint(v);
    return (u16)((u + 0x7FFFu + ((u >> 16) & 1u)) >> 16);
}
__device__ __forceinline__ float bf2f(u16 h) { return __uint_as_float(((unsigned)h) << 16); }

// 4x4 transpose across 4-lane group x 4 regs, add gate biases, LSTM pointwise.
__device__ __forceinline__ void xpose_update(f32x4 acc, int lane,
                                             float bI, float bF, float bG, float bO,
                                             float& cstate, float& h2out) {
    float v0 = acc[0], v1 = acc[1], v2 = acc[2], v3 = acc[3];
    float s0 = __shfl_xor(v0, 1), s1 = __shfl_xor(v1, 1);
    float s2 = __shfl_xor(v2, 1), s3 = __shfl_xor(v3, 1);
    bool b0 = (lane & 1);
    float u0 = b0 ? s1 : v0;
    float u1 = b0 ? v1 : s0;
    float u2 = b0 ? s3 : v2;
    float u3 = b0 ? v3 : s2;
    float t0 = __shfl_xor(u0, 2), t1 = __shfl_xor(u1, 2);
    float t2 = __shfl_xor(u2, 2), t3 = __shfl_xor(u3, 2);
    bool b1 = (lane & 2);
    float w0 = (b1 ? t2 : u0) + bI;   // i
    float w1 = (b1 ? t3 : u1) + bF;   // f
    float w2 = (b1 ? u2 : t0) + bG;   // g
    float w3 = (b1 ? u3 : t1) + bO;   // o
    float c2 = sigf(w1) * cstate + sigf(w0) * tanh_(w2);
    cstate = c2;
    h2out = sigf(w3) * tanh_(c2);
}

// ============================ ENCODER =====================================
__global__ __launch_bounds__(512, 1)
void stgat_enc(const float* __restrict__ obs,
               const float* __restrict__ traj_h0,
               const float* __restrict__ traj_c0,
               const float* __restrict__ graph_h0,
               const float* __restrict__ graph_c0,
               const float* __restrict__ w_ih_t,
               const float* __restrict__ w_hh_t,
               const float* __restrict__ b_ih_t,
               const float* __restrict__ b_hh_t,
               const float* __restrict__ g1w,
               const float* __restrict__ g1as,
               const float* __restrict__ g1ad,
               const float* __restrict__ g1b,
               const float* __restrict__ g2w,
               const float* __restrict__ g2as,
               const float* __restrict__ g2ad,
               const float* __restrict__ g2b,
               const float* __restrict__ w_ih_g,
               const float* __restrict__ w_hh_g,
               const float* __restrict__ b_ih_g,
               const float* __restrict__ b_hh_g,
               float* __restrict__ wsT,          // out: traj_h^T [32][N]
               float* __restrict__ wsG)          // out: graph_h^T [32][N]
{
    const int g    = blockIdx.x;
    const int lane = threadIdx.x & 63;
    const int wv   = __builtin_amdgcn_readfirstlane((int)(threadIdx.x >> 6));
    const int n    = g * NPED + lane;

    __shared__ __attribute__((aligned(16))) u16 ATh[64 * EAP], ATl[64 * EAP]; // traj A (18432 B)
    __shared__ __attribute__((aligned(16))) u16 AGh[64 * EAP], AGl[64 * EAP]; // graph A (18432 B)
    __shared__ float hp1s[4096];   // 16 KB; hp2 overlays first 2048
    __shared__ float scrB2[4096];  // xn = first 2048; x2 = full
    __shared__ float sp1s[512], dp1s[512];  // [half*4+h][64]
    __shared__ float sp2s[512], dp2s[512];  // [w][64]
    __shared__ float biasg[128];
    float* hp2 = hp1s;
    float* xn  = scrB2;
    float* x2  = scrB2;

    const int pfrag = lane & 15, kg8 = (lane >> 4) * 8;
    const int lb2 = lane >> 4, u2 = (lane >> 2) & 3, t_ = lane & 3;
    const int j2 = wv * 4 + u2;      // feature/j owned after transpose

    // ---- W fragments (VGPR-persistent) ----
    short8_t wfhT[2], wflT[2], wfhG[2], wflG[2];
    {
        int gp = wv * 16 + pfrag, j = gp >> 2, ty = gp & 3, orig = ty * 32 + j;
        #pragma unroll
        for (int kb = 0; kb < 2; ++kb) {
            short8_t fhT, flT, fhG, flG;
            #pragma unroll
            for (int jj = 0; jj < 8; ++jj) {
                int k = kb * 32 + (lane >> 4) * 8 + jj;
                float vT, vG;
                if (k < 32)       vT = w_hh_t[orig * 32 + k];
                else if (k < 35)  vT = w_ih_t[orig * 3 + (k - 32)];
                else if (k == 35) vT = b_ih_t[orig] + b_hh_t[orig];
                else              vT = 0.0f;
                if (k < 32)       vG = w_ih_g[orig * 32 + k];
                else              vG = w_hh_g[orig * 32 + (k - 32)];
                u16 hT = bhi(vT); fhT[jj] = (short)hT; flT[jj] = (short)bhi(vT - bf2f(hT));
                u16 hG = bhi(vG); fhG[jj] = (short)hG; flG[jj] = (short)bhi(vG - bf2f(hG));
            }
            wfhT[kb] = fhT; wflT[kb] = flT;
            wfhG[kb] = fhG; wflG[kb] = flG;
        }
    }

    // ---- init A-packs, c-states, bias table ----
    #pragma unroll
    for (int r = 0; r < 4; ++r) {
        int j = wv * 4 + r;
        float vt = traj_h0[n * HT_ + j];
        u16 ht = bhi(vt);
        ATh[lane * EAP + j] = ht;  ATl[lane * EAP + j] = bhi(vt - bf2f(ht));
        float vg = graph_h0[n * HG_ + j];
        u16 hg = bhi(vg);
        AGh[lane * EAP + 32 + j] = hg;  AGl[lane * EAP + 32 + j] = bhi(vg - bf2f(hg));
    }
    float cT2[4], cG2[4];
    #pragma unroll
    for (int mb = 0; mb < 4; ++mb) {
        int p = mb * 16 + lb2 * 4 + t_;
        cT2[mb] = traj_c0[(g * 64 + p) * HT_ + j2];
        cG2[mb] = graph_c0[(g * 64 + p) * HG_ + j2];
    }
    if (wv == 0) {        // x(0) + const-1 col
        #pragma unroll
        for (int c = 0; c < 3; ++c) {
            float v = obs[(0 * NTOT + n) * 3 + c];
            u16 h = bhi(v);
            ATh[lane * EAP + 32 + c] = h;  ATl[lane * EAP + 32 + c] = bhi(v - bf2f(h));
        }
        ATh[lane * EAP + 35] = 0x3F80;  ATl[lane * EAP + 35] = 0;
    } else if (wv == 1) { // zero pad cols 36..63 (avoid NaN garbage in MFMA)
        for (int c = 36; c < 64; ++c) { ATh[lane * EAP + c] = 0; ATl[lane * EAP + c] = 0; }
    }
    if (threadIdx.x < 128) biasg[threadIdx.x] = b_ih_g[threadIdx.x] + b_hh_g[threadIdx.x];
    __syncthreads();

    for (int t = 0; t < OBS; ++t) {
        // ===== T1: traj LSTM via MFMA =====
        float h2T[4], xnv[4];
        {
            f32x4 acc[4];
            #pragma unroll
            for (int mb = 0; mb < 4; ++mb) acc[mb] = (f32x4){0.f, 0.f, 0.f, 0.f};
            #pragma unroll
            for (int kb = 0; kb < 2; ++kb) {
                short8_t ah[4], al[4];
                #pragma unroll
                for (int mb = 0; mb < 4; ++mb) {
                    int off = (mb * 16 + pfrag) * EAP + kb * 32 + kg8;
                    ah[mb] = *(const short8_t*)&ATh[off];
                    al[mb] = *(const short8_t*)&ATl[off];
                }
                #pragma unroll
                for (int mb = 0; mb < 4; ++mb) {
                    acc[mb] = __builtin_amdgcn_mfma_f32_16x16x32_bf16(ah[mb], wfhT[kb], acc[mb], 0, 0, 0);
                    acc[mb] = __builtin_amdgcn_mfma_f32_16x16x32_bf16(ah[mb], wflT[kb], acc[mb], 0, 0, 0);
                    acc[mb] = __builtin_amdgcn_mfma_f32_16x16x32_bf16(al[mb], wfhT[kb], acc[mb], 0, 0, 0);
                }
            }
            #pragma unroll
            for (int mb = 0; mb < 4; ++mb)
                xpose_update(acc[mb], lane, 0.f, 0.f, 0.f, 0.f, cT2[mb], h2T[mb]);
            // inorm over 64 peds for feature j2 (lanes vary bits 0,1,4,5 + mb)
            float sm = h2T[0] + h2T[1] + h2T[2] + h2T[3];
            float sq = h2T[0]*h2T[0] + h2T[1]*h2T[1] + h2T[2]*h2T[2] + h2T[3]*h2T[3];
            sm += __shfl_xor(sm, 1);  sq += __shfl_xor(sq, 1);
            sm += __shfl_xor(sm, 2);  sq += __shfl_xor(sq, 2);
            sm += __shfl_xor(sm, 16); sq += __shfl_xor(sq, 16);
            sm += __shfl_xor(sm, 32); sq += __shfl_xor(sq, 32);
            float mean = sm * (1.0f / 64.0f);
            float var  = sq * (1.0f / 64.0f) - mean * mean;
            float rstd = rsqrtf(var + 1e-5f);
            #pragma unroll
            for (int mb = 0; mb < 4; ++mb) xnv[mb] = (h2T[mb] - mean) * rstd;
        }
        __syncthreads();   // B1: all MFMA reads of AT done
        // ===== T2: write-back h2 + xn; wave0 stages x(t+1) =====
        #pragma unroll
        for (int mb = 0; mb < 4; ++mb) {
            int p = mb * 16 + lb2 * 4 + t_;
            u16 h = bhi(h2T[mb]);
            ATh[p * EAP + j2] = h;  ATl[p * EAP + j2] = bhi(h2T[mb] - bf2f(h));
            xn[j2 * 64 + p] = xnv[mb];
        }
        if (t == OBS - 1) {
            #pragma unroll
            for (int mb = 0; mb < 4; ++mb) {
                int p = mb * 16 + lb2 * 4 + t_;
                wsT[j2 * NTOT + g * 64 + p] = h2T[mb];
            }
        }
        if (wv == 0 && t < OBS - 1) {
            #pragma unroll
            for (int c = 0; c < 3; ++c) {
                float v = obs[((t + 1) * NTOT + n) * 3 + c];
                u16 h = bhi(v);
                ATh[lane * EAP + 32 + c] = h;  ATl[lane * EAP + 32 + c] = bhi(v - bf2f(h));
            }
        }
        __syncthreads();   // B2: xn visible
        // ===== G1: GAT1 projection + s/d partials =====
        {
            const int h_ = wv >> 1;
            const int o0 = (wv & 1) * 8;
            float acc[8];
            #pragma unroll
            for (int q = 0; q < 8; ++q) acc[q] = 0.0f;
            for (int k8 = 0; k8 < 4; ++k8) {
                float xk[8];
                #pragma unroll
                for (int i = 0; i < 8; ++i) xk[i] = xn[(k8 * 8 + i) * 64 + lane];
                #pragma unroll
                for (int i = 0; i < 8; ++i)
                    #pragma unroll
                    for (int q = 0; q < 8; ++q)
                        acc[q] += g1w[h_ * 512 + (k8 * 8 + i) * 16 + o0 + q] * xk[i];
            }
            float ps = 0.0f, pd = 0.0f;
            #pragma unroll
            for (int q = 0; q < 8; ++q) {
                hp1s[(h_ * 16 + o0 + q) * 64 + lane] = acc[q];
                ps += acc[q] * g1as[h_ * 16 + o0 + q];
                pd += acc[q] * g1ad[h_ * 16 + o0 + q];
            }
            sp1s[((wv & 1) * 4 + h_) * 64 + lane] = ps;
            dp1s[((wv & 1) * 4 + h_) * 64 + lane] = pd;
        }
        __syncthreads();   // B3
        // ===== A1: attn1 single-pass + elu + fused inorm -> x2 =====
        {
            const int h_ = wv >> 1;
            const int o0 = (wv & 1) * 8;
            const float sv   = sp1s[h_ * 64 + lane] + sp1s[(4 + h_) * 64 + lane];
            const float dtot = dp1s[h_ * 64 + lane] + dp1s[(4 + h_) * 64 + lane];
            float sum = 0.0f;
            float acc[8];
            #pragma unroll
            for (int q = 0; q < 8; ++q) acc[q] = 0.0f;
            #pragma unroll
            for (int m4 = 0; m4 < 16; ++m4) {
                float e0 = __expf(leaky(sv + __shfl(dtot, m4 * 4 + 0)));
                float e1 = __expf(leaky(sv + __shfl(dtot, m4 * 4 + 1)));
                float e2 = __expf(leaky(sv + __shfl(dtot, m4 * 4 + 2)));
                float e3 = __expf(leaky(sv + __shfl(dtot, m4 * 4 + 3)));
                sum += e0 + e1 + e2 + e3;
                #pragma unroll
                for (int q = 0; q < 8; ++q) {
                    float4 hv = *reinterpret_cast<const float4*>(&hp1s[(h_ * 16 + o0 + q) * 64 + m4 * 4]);
                    acc[q] += e0 * hv.x + e1 * hv.y + e2 * hv.z + e3 * hv.w;
                }
            }
            float rs = 1.0f / sum;
            #pragma unroll
            for (int q = 0; q < 8; ++q) {
                float v = acc[q] * rs + g1b[o0 + q];
                v = (v > 0.0f) ? v : (__expf(v) - 1.0f);          // elu
                float sm = v, sq = v * v;                          // inorm over peds
                #pragma unroll
                for (int m = 1; m < 64; m <<= 1) { sm += __shfl_xor(sm, m); sq += __shfl_xor(sq, m); }
                float mean = sm * (1.0f / 64.0f);
                float var  = sq * (1.0f / 64.0f) - mean * mean;
                x2[(h_ * 16 + o0 + q) * 64 + lane] = (v - mean) * rsqrtf(var + 1e-5f);
            }
        }
        __syncthreads();   // B4
        // ===== G2: GAT2 projection + s2/d2 partials =====
        {
            float acc[4];
            #pragma unroll
            for (int q = 0; q < 4; ++q) acc[q] = 0.0f;
            for (int k8 = 0; k8 < 8; ++k8) {
                float xk[8];
                #pragma unroll
                for (int i = 0; i < 8; ++i) xk[i] = x2[(k8 * 8 + i) * 64 + lane];
                #pragma unroll
                for (int i = 0; i < 8; ++i)
                    #pragma unroll
                    for (int q = 0; q < 4; ++q)
                        acc[q] += g2w[(k8 * 8 + i) * 32 + wv * 4 + q] * xk[i];
            }
            float ps = 0.0f, pd = 0.0f;
            #pragma unroll
            for (int q = 0; q < 4; ++q) {
                hp2[(wv * 4 + q) * 64 + lane] = acc[q];
                ps += acc[q] * g2as[wv * 4 + q];
                pd += acc[q] * g2ad[wv * 4 + q];
            }
            sp2s[wv * 64 + lane] = ps;
            dp2s[wv * 64 + lane] = pd;
        }
        __syncthreads();   // B5 (hp2 overlays hp1s[0:2048]; hp1 dead after A1)
        // ===== A2: attn2 single-pass -> gin cols of AG (bf16 hi/lo) =====
        {
            float sv = 0.0f, dtot = 0.0f;
            #pragma unroll
            for (int w = 0; w < 8; ++w) { sv += sp2s[w * 64 + lane]; dtot += dp2s[w * 64 + lane]; }
            float sum = 0.0f;
            float acc[4];
            #pragma unroll
            for (int q = 0; q < 4; ++q) acc[q] = 0.0f;
            #pragma unroll
            for (int m4 = 0; m4 < 16; ++m4) {
                float e0 = __expf(leaky(sv + __shfl(dtot, m4 * 4 + 0)));
                float e1 = __expf(leaky(sv + __shfl(dtot, m4 * 4 + 1)));
                float e2 = __expf(leaky(sv + __shfl(dtot, m4 * 4 + 2)));
                float e3 = __expf(leaky(sv + __shfl(dtot, m4 * 4 + 3)));
                sum += e0 + e1 + e2 + e3;
                #pragma unroll
                for (int q = 0; q < 4; ++q) {
                    float4 hv = *reinterpret_cast<const float4*>(&hp2[(wv * 4 + q) * 64 + m4 * 4]);
                    acc[q] += e0 * hv.x + e1 * hv.y + e2 * hv.z + e3 * hv.w;
                }
            }
            float rs = 1.0f / sum;
            #pragma unroll
            for (int q = 0; q < 4; ++q) {
                float v = acc[q] * rs + g2b[wv * 4 + q];
                u16 h = bhi(v);
                AGh[lane * EAP + wv * 4 + q] = h;
                AGl[lane * EAP + wv * 4 + q] = bhi(v - bf2f(h));
            }
        }
        __syncthreads();   // B6: AG gin cols visible
        // ===== GR1: graph LSTM via MFMA =====
        float h2G[4];
        {
            f32x4 acc[4];
            #pragma unroll
            for (int mb = 0; mb < 4; ++mb) acc[mb] = (f32x4){0.f, 0.f, 0.f, 0.f};
            #pragma unroll
            for (int kb = 0; kb < 2; ++kb) {
                short8_t ah[4], al[4];
                #pragma unroll
                for (int mb = 0; mb < 4; ++mb) {
                    int off = (mb * 16 + pfrag) * EAP + kb * 32 + kg8;
                    ah[mb] = *(const short8_t*)&AGh[off];
                    al[mb] = *(const short8_t*)&AGl[off];
                }
                #pragma unroll
                for (int mb = 0; mb < 4; ++mb) {
                    acc[mb] = __builtin_amdgcn_mfma_f32_16x16x32_bf16(ah[mb], wfhG[kb], acc[mb], 0, 0, 0);
                    acc[mb] = __builtin_amdgcn_mfma_f32_16x16x32_bf16(ah[mb], wflG[kb], acc[mb], 0, 0, 0);
                    acc[mb] = __builtin_amdgcn_mfma_f32_16x16x32_bf16(al[mb], wfhG[kb], acc[mb], 0, 0, 0);
                }
            }
            const float bI = biasg[j2], bF = biasg[32 + j2], bG = biasg[64 + j2], bO = biasg[96 + j2];
            #pragma unroll
            for (int mb = 0; mb < 4; ++mb)
                xpose_update(acc[mb], lane, bI, bF, bG, bO, cG2[mb], h2G[mb]);
        }
        __syncthreads();   // B7: all MFMA reads of AG done
        // ===== GR2: write-back graph h2 =====
        #pragma unroll
        for (int mb = 0; mb < 4; ++mb) {
            int p = mb * 16 + lb2 * 4 + t_;
            u16 h = bhi(h2G[mb]);
            AGh[p * EAP + 32 + j2] = h;  AGl[p * EAP + 32 + j2] = bhi(h2G[mb] - bf2f(h));
        }
        if (t == OBS - 1) {
            #pragma unroll
            for (int mb = 0; mb < 4; ++mb) {
                int p = mb * 16 + lb2 * 4 + t_;
                wsG[j2 * NTOT + g * 64 + p] = h2G[mb];
            }
        }
        // no barrier: next reads of AG are behind B6 of t+1; AT reads behind B1 path
    } // t loop
}

// ============================ DECODER (round-5, unchanged) =================
__global__ __launch_bounds__(512, 1)
void stgat_dec(const float* __restrict__ obs,
               const float* __restrict__ zin,
               const float* __restrict__ w_ih_p,
               const float* __restrict__ w_hh_p,
               const float* __restrict__ b_ih_p,
               const float* __restrict__ b_hh_p,
               const float* __restrict__ w_out,
               const float* __restrict__ b_out,
               const float* __restrict__ wsT,    // traj_h^T [32][N]
               const float* __restrict__ wsG,    // graph_h^T [32][N]
               float* __restrict__ out)
{
    const int g    = blockIdx.x;
    const int lane = threadIdx.x & 63;
    const int wv   = __builtin_amdgcn_readfirstlane((int)(threadIdx.x >> 6));
    const int n    = g * NPED + lane;

    __shared__ __attribute__((aligned(16))) u16 Apack[4 * 64 * AP];
    __shared__ __attribute__((aligned(16))) short8_t WloS[18 * 3 * 64];
    u16* AhiA = Apack;
    u16* AloA = AhiA + 64 * AP;
    u16* AhiB = AloA + 64 * AP;
    u16* AloB = AhiB + 64 * AP;

    short8_t wfh[3][3];
    {
        const int col = lane & 15, lb = lane >> 4;
        #pragma unroll
        for (int s = 0; s < 3; ++s) {
            if (s < 2 || wv < 2) {
                int nb = wv + 8 * s;
                int gp = nb * 16 + col;
                int j = gp >> 2, ty = gp & 3;
                int orig = ty * HP_ + j;
                #pragma unroll
                for (int kb = 0; kb < 3; ++kb) {
                    short8_t fh, fl;
                    #pragma unroll
                    for (int jj = 0; jj < 8; ++jj) {
                        int k = kb * 32 + lb * 8 + jj;
                        float v;
                        if (k < 72)       v = w_hh_p[orig * HP_ + k];
                        else if (k == 72) v = w_ih_p[orig * 2 + 0];
                        else if (k == 73) v = w_ih_p[orig * 2 + 1];
                        else if (k == 74) v = b_ih_p[orig] + b_hh_p[orig];
                        else              v = 0.0f;
                        u16 hb = bhi(v);
                        fh[jj] = (short)hb;
                        fl[jj] = (short)bhi(v - bf2f(hb));
                    }
                    wfh[s][kb] = fh;
                    WloS[(nb * 3 + kb) * 64 + lane] = fl;
                }
            }
        }
    }

    {
        float px0 = obs[(7 * NTOT + n) * 3 + 0];
        float px1 = obs[(7 * NTOT + n) * 3 + 1];
        #pragma unroll
        for (int kk = 0; kk < 12; ++kk) {
            int k = wv + kk * 8;
            float va, vb;
            if (k < 32)       { va = wsT[k * NTOT + n];            vb = 0.0f; }
            else if (k < 64)  { va = vb = wsG[(k - 32) * NTOT + n]; }
            else if (k < 72)  { va = vb = zin[g * NZ_ + (k - 64)]; }
            else if (k == 72) { va = vb = px0; }
            else if (k == 73) { va = vb = px1; }
            else if (k == 74) { va = vb = 1.0f; }
            else              { va = vb = 0.0f; }
            u16 ha = bhi(va); u16 la = bhi(va - bf2f(ha));
            u16 hb = bhi(vb); u16 lb_ = bhi(vb - bf2f(hb));
            AhiA[lane * AP + k] = ha;  AloA[lane * AP + k] = la;
            AhiB[lane * AP + k] = hb;  AloB[lane * AP + k] = lb_;
        }
    }
    __syncthreads();

    float cstA[3][4], cstB[3][4];
    #pragma unroll
    for (int s = 0; s < 3; ++s)
        #pragma unroll
        for (int mb = 0; mb < 4; ++mb) { cstA[s][mb] = 0.0f; cstB[s][mb] = 0.0f; }

    const int lb2 = lane >> 4, u_ = (lane >> 2) & 3, t_ = lane & 3;
    const int pfrag = lane & 15, kgrp = (lane >> 4) * 8;

    for (int st = 0; st < FUT; ++st) {
        float h2A[3][4], h2B[3][4];
        {
            f32x4 acc[3][4];
            #pragma unroll
            for (int s = 0; s < 3; ++s)
                #pragma unroll
                for (int mb = 0; mb < 4; ++mb) acc[s][mb] = (f32x4){0.f, 0.f, 0.f, 0.f};
            #pragma unroll
            for (int kb = 0; kb < 3; ++kb) {
                short8_t ah[4], al[4];
                #pragma unroll
                for (int mb = 0; mb < 4; ++mb) {
                    int off = (mb * 16 + pfrag) * AP + kb * 32 + kgrp;
                    ah[mb] = *(const short8_t*)&AhiA[off];
                    al[mb] = *(const short8_t*)&AloA[off];
                }
                #pragma unroll
                for (int s = 0; s < 3; ++s) {
                    if (s < 2 || wv < 2) {
                        int nb = wv + 8 * s;
                        short8_t wl = WloS[(nb * 3 + kb) * 64 + lane];
                        #pragma unroll
                        for (int mb = 0; mb < 4; ++mb) {
                            acc[s][mb] = __builtin_amdgcn_mfma_f32_16x16x32_bf16(ah[mb], wfh[s][kb], acc[s][mb], 0, 0, 0);
                            acc[s][mb] = __builtin_amdgcn_mfma_f32_16x16x32_bf16(ah[mb], wl,         acc[s][mb], 0, 0, 0);
                            acc[s][mb] = __builtin_amdgcn_mfma_f32_16x16x32_bf16(al[mb], wfh[s][kb], acc[s][mb], 0, 0, 0);
                        }
                    }
                }
            }
            #pragma unroll
            for (int s = 0; s < 3; ++s)
                #pragma unroll
                for (int mb = 0; mb < 4; ++mb)
                    xpose_update(acc[s][mb], lane, 0.f, 0.f, 0.f, 0.f, cstA[s][mb], h2A[s][mb]);
        }
        {
            f32x4 acc[3][4];
            #pragma unroll
            for (int s = 0; s < 3; ++s)
                #pragma unroll
                for (int mb = 0; mb < 4; ++mb) acc[s][mb] = (f32x4){0.f, 0.f, 0.f, 0.f};
            #pragma unroll
            for (int kb = 0; kb < 3; ++kb) {
                short8_t bh[4], bl[4];
                #pragma unroll
                for (int mb = 0; mb < 4; ++mb) {
                    int off = (mb * 16 + pfrag) * AP + kb * 32 + kgrp;
                    bh[mb] = *(const short8_t*)&AhiB[off];
                    bl[mb] = *(const short8_t*)&AloB[off];
                }
                #pragma unroll
                for (int s = 0; s < 3; ++s) {
                    if (s < 2 || wv < 2) {
                        int nb = wv + 8 * s;
                        short8_t wl = WloS[(nb * 3 + kb) * 64 + lane];
                        #pragma unroll
                        for (int mb = 0; mb < 4; ++mb) {
                            acc[s][mb] = __builtin_amdgcn_mfma_f32_16x16x32_bf16(bh[mb], wfh[s][kb], acc[s][mb], 0, 0, 0);
                            acc[s][mb] = __builtin_amdgcn_mfma_f32_16x16x32_bf16(bh[mb], wl,         acc[s][mb], 0, 0, 0);
                            acc[s][mb] = __builtin_amdgcn_mfma_f32_16x16x32_bf16(bl[mb], wfh[s][kb], acc[s][mb], 0, 0, 0);
                        }
                    }
                }
            }
            #pragma unroll
            for (int s = 0; s < 3; ++s)
                #pragma unroll
                for (int mb = 0; mb < 4; ++mb)
                    xpose_update(acc[s][mb], lane, 0.f, 0.f, 0.f, 0.f, cstB[s][mb], h2B[s][mb]);
        }
        __syncthreads();   // B1
        #pragma unroll
        for (int s = 0; s < 3; ++s) {
            if (s < 2 || wv < 2) {
                int nb = wv + 8 * s;
                int j = nb * 4 + u_;
                #pragma unroll
                for (int mb = 0; mb < 4; ++mb) {
                    int p = mb * 16 + lb2 * 4 + t_;
                    float va = h2A[s][mb];
                    float vb = h2B[s][mb];
                    u16 ha = bhi(va);
                    AhiA[p * AP + j] = ha;  AloA[p * AP + j] = bhi(va - bf2f(ha));
                    u16 hb = bhi(vb);
                    AhiB[p * AP + j] = hb;  AloB[p * AP + j] = bhi(vb - bf2f(hb));
                }
            }
        }
        __syncthreads();   // B2
        if (wv == 0) {
            float s0 = 0.0f, s1_ = 0.0f;
            #pragma unroll
            for (int jb = 0; jb < 9; ++jb) {
                short8_t xha = *(const short8_t*)&AhiA[lane * AP + jb * 8];
                short8_t xla = *(const short8_t*)&AloA[lane * AP + jb * 8];
                short8_t xhb = *(const short8_t*)&AhiB[lane * AP + jb * 8];
                short8_t xlb = *(const short8_t*)&AloB[lane * AP + jb * 8];
                #pragma unroll
                for (int jj = 0; jj < 8; ++jj) {
                    int j = jb * 8 + jj;
                    float dh = (bf2f((u16)xha[jj]) + bf2f((u16)xla[jj]))
                             - (bf2f((u16)xhb[jj]) + bf2f((u16)xlb[jj]));
                    s0  += w_out[j] * dh;
                    s1_ += w_out[HP_ + j] * dh;
                }
            }
            float o0 = s0 + b_out[0], o1 = s1_ + b_out[1];
            *reinterpret_cast<float2*>(&out[(size_t)(st * NTOT + n) * 2]) = make_float2(o0, o1);
            u16 h0 = bhi(o0); u16 l0 = bhi(o0 - bf2f(h0));
            u16 h1 = bhi(o1); u16 l1 = bhi(o1 - bf2f(h1));
            AhiA[lane * AP + 72] = h0;  AloA[lane * AP + 72] = l0;
            AhiB[lane * AP + 72] = h0;  AloB[lane * AP + 72] = l0;
            AhiA[lane * AP + 73] = h1;  AloA[lane * AP + 73] = l1;
            AhiB[lane * AP + 73] = h1;  AloB[lane * AP + 73] = l1;
        }
        __syncthreads();   // B3
    }
}

extern "C" void kernel_launch(void* const* d_in, const int* in_sizes, int n_in,
                              void* d_out, int out_size, void* d_ws, size_t ws_size,
                              hipStream_t stream) {
    (void)in_sizes; (void)n_in; (void)out_size; (void)ws_size;
    float* wsT = (float*)d_ws;                 // [32][N]
    float* wsG = wsT + (size_t)HT_ * NTOT;     // [32][N]

    stgat_enc<<<dim3(NGR), dim3(512), 0, stream>>>(
        (const float*)d_in[0],
        (const float*)d_in[2],  (const float*)d_in[3],
        (const float*)d_in[4],  (const float*)d_in[5],
        (const float*)d_in[6],  (const float*)d_in[7],  (const float*)d_in[8],  (const float*)d_in[9],
        (const float*)d_in[10], (const float*)d_in[11], (const float*)d_in[12], (const float*)d_in[13],
        (const float*)d_in[14], (const float*)d_in[15], (const float*)d_in[16], (const float*)d_in[17],
        (const float*)d_in[18], (const float*)d_in[19], (const float*)d_in[20], (const float*)d_in[21],
        wsT, wsG);

    stgat_dec<<<dim3(NGR), dim3(512), 0, stream>>>(
        (const float*)d_in[0],
        (const float*)d_in[1],
        (const float*)d_in[22], (const float*)d_in[23],
        (const float*)d_in[24], (const float*)d_in[25],
        (const float*)d_in[26], (const float*)d_in[27],
        wsT, wsG,
        (float*)d_out);
}

// Round 8
// 1475.547 us; speedup vs baseline: 1.0272x; 1.0272x over previous
//
#include <hip/hip_runtime.h>

// STGAT round 8: restructure for parallelism.
//  A: traj LSTM, thread-per-ped (wave=graph), ZERO barriers, h/c in LDS-private.
//  B: GAT, grid 8192 = (t,g) -- the 8 timesteps are independent. 4 barriers/block.
//  C: graph LSTM, r7 MFMA form, 2 barriers/t.
//  D: decoder, r5 math, B3 removed (redundant all-wave output dot).
// Falls back to the round-7 monolithic encoder if ws_size < ~151MB.

#define OBS 8
#define FUT 12
#define NPED 64
#define HT_ 32
#define HG_ 32
#define NZ_ 8
#define HP_ 72
#define NGR 1024
#define NTOT (NGR * NPED)
#define AP 104
#define EAP 72

typedef __attribute__((ext_vector_type(8))) short short8_t;
typedef __attribute__((ext_vector_type(4))) float f32x4;
typedef unsigned short u16;

__device__ __forceinline__ float sigf(float x) { return 1.0f / (1.0f + __expf(-x)); }
__device__ __forceinline__ float tanh_(float x) {
    float e = __expf(2.0f * x);
    return 1.0f - 2.0f / (e + 1.0f);
}
__device__ __forceinline__ float leaky(float x) { return (x > 0.0f) ? x : 0.2f * x; }
__device__ __forceinline__ u16 bhi(float v) {
    unsigned u = __float_as_uint(v);
    return (u16)((u + 0x7FFFu + ((u >> 16) & 1u)) >> 16);
}
__device__ __forceinline__ float bf2f(u16 h) { return __uint_as_float(((unsigned)h) << 16); }

__device__ __forceinline__ void xpose_update(f32x4 acc, int lane,
                                             float bI, float bF, float bG, float bO,
                                             float& cstate, float& h2out) {
    float v0 = acc[0], v1 = acc[1], v2 = acc[2], v3 = acc[3];
    float s0 = __shfl_xor(v0, 1), s1 = __shfl_xor(v1, 1);
    float s2 = __shfl_xor(v2, 1), s3 = __shfl_xor(v3, 1);
    bool b0 = (lane & 1);
    float u0 = b0 ? s1 : v0;
    float u1 = b0 ? v1 : s0;
    float u2 = b0 ? s3 : v2;
    float u3 = b0 ? v3 : s2;
    float t0 = __shfl_xor(u0, 2), t1 = __shfl_xor(u1, 2);
    float t2 = __shfl_xor(u2, 2), t3 = __shfl_xor(u3, 2);
    bool b1 = (lane & 2);
    float w0 = (b1 ? t2 : u0) + bI;
    float w1 = (b1 ? t3 : u1) + bF;
    float w2 = (b1 ? u2 : t0) + bG;
    float w3 = (b1 ? u3 : t1) + bO;
    float c2 = sigf(w1) * cstate + sigf(w0) * tanh_(w2);
    cstate = c2;
    h2out = sigf(w3) * tanh_(c2);
}

// ====================== A: traj LSTM (no barriers) ========================
__global__ __launch_bounds__(256, 1)
void traj_lstm_k(const float* __restrict__ obs,
                 const float* __restrict__ h0,
                 const float* __restrict__ c0,
                 const float* __restrict__ w_ih,
                 const float* __restrict__ w_hh,
                 const float* __restrict__ b_ih,
                 const float* __restrict__ b_hh,
                 float* __restrict__ ws1,    // xn f32 [8][32][N]
                 float* __restrict__ wsT)    // raw h at t=7, [32][N]
{
    const int tid = threadIdx.x;
    const int n   = blockIdx.x * 256 + tid;
    __shared__ __attribute__((aligned(16))) float W[128 * 36];   // [gate][h32|x3|bias]
    __shared__ float hc[256 * 33 * 2];                           // stride 33: conflict-free
    float* hl = &hc[tid * 33];
    float* cl = &hc[(256 + tid) * 33];

    for (int i = tid; i < 128 * 36; i += 256) {
        int gate = i / 36, k = i - gate * 36;
        float v;
        if (k < 32)      v = w_hh[gate * 32 + k];
        else if (k < 35) v = w_ih[gate * 3 + (k - 32)];
        else             v = b_ih[gate] + b_hh[gate];
        W[i] = v;
    }
    #pragma unroll
    for (int j4 = 0; j4 < 8; ++j4) {
        f32x4 hv = *(const f32x4*)&h0[(size_t)n * 32 + j4 * 4];
        f32x4 cv = *(const f32x4*)&c0[(size_t)n * 32 + j4 * 4];
        #pragma unroll
        for (int r = 0; r < 4; ++r) { hl[j4 * 4 + r] = hv[r]; cl[j4 * 4 + r] = cv[r]; }
    }
    __syncthreads();   // only barrier: W staged

    for (int t = 0; t < OBS; ++t) {
        f32x4 v4[9];
        #pragma unroll
        for (int kq = 0; kq < 8; ++kq) {
            f32x4 x;
            #pragma unroll
            for (int r = 0; r < 4; ++r) x[r] = hl[kq * 4 + r];
            v4[kq] = x;
        }
        {
            const float* ob = &obs[((size_t)t * NTOT + n) * 3];
            v4[8] = (f32x4){ob[0], ob[1], ob[2], 1.0f};
        }
        #pragma unroll 4
        for (int j = 0; j < 32; ++j) {
            f32x4 ai = {0,0,0,0}, af4 = {0,0,0,0}, ag4 = {0,0,0,0}, ao4 = {0,0,0,0};
            #pragma unroll
            for (int kq = 0; kq < 9; ++kq) {
                ai  += *(const f32x4*)&W[(j)      * 36 + kq * 4] * v4[kq];
                af4 += *(const f32x4*)&W[(32 + j) * 36 + kq * 4] * v4[kq];
                ag4 += *(const f32x4*)&W[(64 + j) * 36 + kq * 4] * v4[kq];
                ao4 += *(const f32x4*)&W[(96 + j) * 36 + kq * 4] * v4[kq];
            }
            float gi = (ai[0]  + ai[1])  + (ai[2]  + ai[3]);
            float gf = (af4[0] + af4[1]) + (af4[2] + af4[3]);
            float gg = (ag4[0] + ag4[1]) + (ag4[2] + ag4[3]);
            float go = (ao4[0] + ao4[1]) + (ao4[2] + ao4[3]);
            float cc = sigf(gf) * cl[j] + sigf(gi) * tanh_(gg);
            cl[j] = cc;
            hl[j] = sigf(go) * tanh_(cc);
        }
        // inorm over the 64 peds of this wave's graph (wave == graph)
        #pragma unroll 4
        for (int f = 0; f < 32; ++f) {
            float v = hl[f];
            float sm = v, sq = v * v;
            #pragma unroll
            for (int m = 1; m < 64; m <<= 1) { sm += __shfl_xor(sm, m); sq += __shfl_xor(sq, m); }
            float mean = sm * (1.0f / 64.0f);
            float var  = sq * (1.0f / 64.0f) - mean * mean;
            ws1[((size_t)t * 32 + f) * NTOT + n] = (v - mean) * rsqrtf(var + 1e-5f);
        }
        if (t == OBS - 1) {
            #pragma unroll 4
            for (int f = 0; f < 32; ++f) wsT[(size_t)f * NTOT + n] = hl[f];
        }
    }
}

// ====================== B: GAT, one block per (t,g) =======================
__global__ __launch_bounds__(512, 2)
void gat_k(const float* __restrict__ ws1,   // xn [8][32][N]
           const float* __restrict__ g1w,
           const float* __restrict__ g1as,
           const float* __restrict__ g1ad,
           const float* __restrict__ g1b,
           const float* __restrict__ g2w,
           const float* __restrict__ g2as,
           const float* __restrict__ g2ad,
           const float* __restrict__ g2b,
           float* __restrict__ ws2)         // gin [8][32][N]
{
    const int t    = blockIdx.x >> 10;
    const int g    = blockIdx.x & 1023;
    const int lane = threadIdx.x & 63;
    const int wv   = __builtin_amdgcn_readfirstlane((int)(threadIdx.x >> 6));

    __shared__ float hp1s[4096];   // hp2 overlays first 2048
    __shared__ float xnx[4096];    // xn = first 2048; x2 = full
    __shared__ float sp1s[512], dp1s[512], sp2s[512], dp2s[512];
    float* xn  = xnx;
    float* x2  = xnx;
    float* hp2 = hp1s;

    #pragma unroll
    for (int r = 0; r < 4; ++r) {
        int f = wv * 4 + r;
        xn[f * 64 + lane] = ws1[((size_t)t * 32 + f) * NTOT + g * 64 + lane];
    }
    __syncthreads();
    // ===== G1: GAT1 projection + s/d partials =====
    {
        const int h_ = wv >> 1;
        const int o0 = (wv & 1) * 8;
        float acc[8];
        #pragma unroll
        for (int q = 0; q < 8; ++q) acc[q] = 0.0f;
        for (int k8 = 0; k8 < 4; ++k8) {
            float xk[8];
            #pragma unroll
            for (int i = 0; i < 8; ++i) xk[i] = xn[(k8 * 8 + i) * 64 + lane];
            #pragma unroll
            for (int i = 0; i < 8; ++i)
                #pragma unroll
                for (int q = 0; q < 8; ++q)
                    acc[q] += g1w[h_ * 512 + (k8 * 8 + i) * 16 + o0 + q] * xk[i];
        }
        float ps = 0.0f, pd = 0.0f;
        #pragma unroll
        for (int q = 0; q < 8; ++q) {
            hp1s[(h_ * 16 + o0 + q) * 64 + lane] = acc[q];
            ps += acc[q] * g1as[h_ * 16 + o0 + q];
            pd += acc[q] * g1ad[h_ * 16 + o0 + q];
        }
        sp1s[((wv & 1) * 4 + h_) * 64 + lane] = ps;
        dp1s[((wv & 1) * 4 + h_) * 64 + lane] = pd;
    }
    __syncthreads();
    // ===== A1: attn1 single-pass + elu + fused inorm -> x2 =====
    {
        const int h_ = wv >> 1;
        const int o0 = (wv & 1) * 8;
        const float sv   = sp1s[h_ * 64 + lane] + sp1s[(4 + h_) * 64 + lane];
        const float dtot = dp1s[h_ * 64 + lane] + dp1s[(4 + h_) * 64 + lane];
        float sum = 0.0f;
        float acc[8];
        #pragma unroll
        for (int q = 0; q < 8; ++q) acc[q] = 0.0f;
        #pragma unroll
        for (int m4 = 0; m4 < 16; ++m4) {
            float e0 = __expf(leaky(sv + __shfl(dtot, m4 * 4 + 0)));
            float e1 = __expf(leaky(sv + __shfl(dtot, m4 * 4 + 1)));
            float e2 = __expf(leaky(sv + __shfl(dtot, m4 * 4 + 2)));
            float e3 = __expf(leaky(sv + __shfl(dtot, m4 * 4 + 3)));
            sum += e0 + e1 + e2 + e3;
            #pragma unroll
            for (int q = 0; q < 8; ++q) {
                float4 hv = *reinterpret_cast<const float4*>(&hp1s[(h_ * 16 + o0 + q) * 64 + m4 * 4]);
                acc[q] += e0 * hv.x + e1 * hv.y + e2 * hv.z + e3 * hv.w;
            }
        }
        float rs = 1.0f / sum;
        #pragma unroll
        for (int q = 0; q < 8; ++q) {
            float v = acc[q] * rs + g1b[o0 + q];
            v = (v > 0.0f) ? v : (__expf(v) - 1.0f);
            float sm = v, sq = v * v;
            #pragma unroll
            for (int m = 1; m < 64; m <<= 1) { sm += __shfl_xor(sm, m); sq += __shfl_xor(sq, m); }
            float mean = sm * (1.0f / 64.0f);
            float var  = sq * (1.0f / 64.0f) - mean * mean;
            x2[(h_ * 16 + o0 + q) * 64 + lane] = (v - mean) * rsqrtf(var + 1e-5f);
        }
    }
    __syncthreads();
    // ===== G2: GAT2 projection + s2/d2 partials =====
    {
        float acc[4];
        #pragma unroll
        for (int q = 0; q < 4; ++q) acc[q] = 0.0f;
        for (int k8 = 0; k8 < 8; ++k8) {
            float xk[8];
            #pragma unroll
            for (int i = 0; i < 8; ++i) xk[i] = x2[(k8 * 8 + i) * 64 + lane];
            #pragma unroll
            for (int i = 0; i < 8; ++i)
                #pragma unroll
                for (int q = 0; q < 4; ++q)
                    acc[q] += g2w[(k8 * 8 + i) * 32 + wv * 4 + q] * xk[i];
        }
        float ps = 0.0f, pd = 0.0f;
        #pragma unroll
        for (int q = 0; q < 4; ++q) {
            hp2[(wv * 4 + q) * 64 + lane] = acc[q];
            ps += acc[q] * g2as[wv * 4 + q];
            pd += acc[q] * g2ad[wv * 4 + q];
        }
        sp2s[wv * 64 + lane] = ps;
        dp2s[wv * 64 + lane] = pd;
    }
    __syncthreads();
    // ===== A2: attn2 single-pass -> gin (global) =====
    {
        float sv = 0.0f, dtot = 0.0f;
        #pragma unroll
        for (int w = 0; w < 8; ++w) { sv += sp2s[w * 64 + lane]; dtot += dp2s[w * 64 + lane]; }
        float sum = 0.0f;
        float acc[4];
        #pragma unroll
        for (int q = 0; q < 4; ++q) acc[q] = 0.0f;
        #pragma unroll
        for (int m4 = 0; m4 < 16; ++m4) {
            float e0 = __expf(leaky(sv + __shfl(dtot, m4 * 4 + 0)));
            float e1 = __expf(leaky(sv + __shfl(dtot, m4 * 4 + 1)));
            float e2 = __expf(leaky(sv + __shfl(dtot, m4 * 4 + 2)));
            float e3 = __expf(leaky(sv + __shfl(dtot, m4 * 4 + 3)));
            sum += e0 + e1 + e2 + e3;
            #pragma unroll
            for (int q = 0; q < 4; ++q) {
                float4 hv = *reinterpret_cast<const float4*>(&hp2[(wv * 4 + q) * 64 + m4 * 4]);
                acc[q] += e0 * hv.x + e1 * hv.y + e2 * hv.z + e3 * hv.w;
            }
        }
        float rs = 1.0f / sum;
        #pragma unroll
        for (int q = 0; q < 4; ++q)
            ws2[((size_t)t * 32 + wv * 4 + q) * NTOT + g * 64 + lane] = acc[q] * rs + g2b[wv * 4 + q];
    }
}

// ====================== C: graph LSTM (MFMA, 2 barriers/t) ================
__global__ __launch_bounds__(512, 1)
void graph_lstm_k(const float* __restrict__ ws2,      // gin [8][32][N]
                  const float* __restrict__ graph_h0,
                  const float* __restrict__ graph_c0,
                  const float* __restrict__ w_ih_g,
                  const float* __restrict__ w_hh_g,
                  const float* __restrict__ b_ih_g,
                  const float* __restrict__ b_hh_g,
                  float* __restrict__ wsG)             // out [32][N]
{
    const int g    = blockIdx.x;
    const int lane = threadIdx.x & 63;
    const int wv   = __builtin_amdgcn_readfirstlane((int)(threadIdx.x >> 6));
    const int n    = g * NPED + lane;

    __shared__ __attribute__((aligned(16))) u16 AGh[64 * EAP], AGl[64 * EAP];
    __shared__ float biasg[128];

    const int pfrag = lane & 15, kg8 = (lane >> 4) * 8;
    const int lb2 = lane >> 4, u2 = (lane >> 2) & 3, t_ = lane & 3;
    const int j2 = wv * 4 + u2;

    short8_t wfhG[2], wflG[2];
    {
        int gp = wv * 16 + pfrag, j = gp >> 2, ty = gp & 3, orig = ty * 32 + j;
        #pragma unroll
        for (int kb = 0; kb < 2; ++kb) {
            short8_t fhG, flG;
            #pragma unroll
            for (int jj = 0; jj < 8; ++jj) {
                int k = kb * 32 + (lane >> 4) * 8 + jj;
                float vG = (k < 32) ? w_ih_g[orig * 32 + k] : w_hh_g[orig * 32 + (k - 32)];
                u16 hG = bhi(vG); fhG[jj] = (short)hG; flG[jj] = (short)bhi(vG - bf2f(hG));
            }
            wfhG[kb] = fhG; wflG[kb] = flG;
        }
    }
    #pragma unroll
    for (int r = 0; r < 4; ++r) {
        int j = wv * 4 + r;
        float vg = graph_h0[(size_t)n * HG_ + j];
        u16 hg = bhi(vg);
        AGh[lane * EAP + 32 + j] = hg;  AGl[lane * EAP + 32 + j] = bhi(vg - bf2f(hg));
    }
    float cG2[4];
    #pragma unroll
    for (int mb = 0; mb < 4; ++mb) {
        int p = mb * 16 + lb2 * 4 + t_;
        cG2[mb] = graph_c0[(size_t)(g * 64 + p) * HG_ + j2];
    }
    if (threadIdx.x < 128) biasg[threadIdx.x] = b_ih_g[threadIdx.x] + b_hh_g[threadIdx.x];

    for (int t = 0; t < OBS; ++t) {
        // stage gin cols 0..31 (h cols 32..63 written by prev GR2: disjoint)
        #pragma unroll
        for (int r = 0; r < 4; ++r) {
            int f = wv * 4 + r;
            float v = ws2[((size_t)t * 32 + f) * NTOT + g * 64 + lane];
            u16 h = bhi(v);
            AGh[lane * EAP + f] = h;  AGl[lane * EAP + f] = bhi(v - bf2f(h));
        }
        __syncthreads();   // B1: gin + prev h published
        float h2G[4];
        {
            f32x4 acc[4];
            #pragma unroll
            for (int mb = 0; mb < 4; ++mb) acc[mb] = (f32x4){0.f, 0.f, 0.f, 0.f};
            #pragma unroll
            for (int kb = 0; kb < 2; ++kb) {
                short8_t ah[4], al[4];
                #pragma unroll
                for (int mb = 0; mb < 4; ++mb) {
                    int off = (mb * 16 + pfrag) * EAP + kb * 32 + kg8;
                    ah[mb] = *(const short8_t*)&AGh[off];
                    al[mb] = *(const short8_t*)&AGl[off];
                }
                #pragma unroll
                for (int mb = 0; mb < 4; ++mb) {
                    acc[mb] = __builtin_amdgcn_mfma_f32_16x16x32_bf16(ah[mb], wfhG[kb], acc[mb], 0, 0, 0);
                    acc[mb] = __builtin_amdgcn_mfma_f32_16x16x32_bf16(ah[mb], wflG[kb], acc[mb], 0, 0, 0);
                    acc[mb] = __builtin_amdgcn_mfma_f32_16x16x32_bf16(al[mb], wfhG[kb], acc[mb], 0, 0, 0);
                }
            }
            const float bI = biasg[j2], bF = biasg[32 + j2], bG = biasg[64 + j2], bO = biasg[96 + j2];
            #pragma unroll
            for (int mb = 0; mb < 4; ++mb)
                xpose_update(acc[mb], lane, bI, bF, bG, bO, cG2[mb], h2G[mb]);
        }
        __syncthreads();   // B2: reads of AG done
        #pragma unroll
        for (int mb = 0; mb < 4; ++mb) {
            int p = mb * 16 + lb2 * 4 + t_;
            u16 h = bhi(h2G[mb]);
            AGh[p * EAP + 32 + j2] = h;  AGl[p * EAP + 32 + j2] = bhi(h2G[mb] - bf2f(h));
        }
        if (t == OBS - 1) {
            #pragma unroll
            for (int mb = 0; mb < 4; ++mb) {
                int p = mb * 16 + lb2 * 4 + t_;
                wsG[(size_t)j2 * NTOT + g * 64 + p] = h2G[mb];
            }
        }
    }
}

// ============ Fallback encoder (round-7, verbatim) =========================
__global__ __launch_bounds__(512, 1)
void stgat_enc(const float* __restrict__ obs,
               const float* __restrict__ traj_h0,
               const float* __restrict__ traj_c0,
               const float* __restrict__ graph_h0,
               const float* __restrict__ graph_c0,
               const float* __restrict__ w_ih_t,
               const float* __restrict__ w_hh_t,
               const float* __restrict__ b_ih_t,
               const float* __restrict__ b_hh_t,
               const float* __restrict__ g1w,
               const float* __restrict__ g1as,
               const float* __restrict__ g1ad,
               const float* __restrict__ g1b,
               const float* __restrict__ g2w,
               const float* __restrict__ g2as,
               const float* __restrict__ g2ad,
               const float* __restrict__ g2b,
               const float* __restrict__ w_ih_g,
               const float* __restrict__ w_hh_g,
               const float* __restrict__ b_ih_g,
               const float* __restrict__ b_hh_g,
               float* __restrict__ wsT,
               float* __restrict__ wsG)
{
    const int g    = blockIdx.x;
    const int lane = threadIdx.x & 63;
    const int wv   = __builtin_amdgcn_readfirstlane((int)(threadIdx.x >> 6));
    const int n    = g * NPED + lane;

    __shared__ __attribute__((aligned(16))) u16 ATh[64 * EAP], ATl[64 * EAP];
    __shared__ __attribute__((aligned(16))) u16 AGh[64 * EAP], AGl[64 * EAP];
    __shared__ float hp1s[4096];
    __shared__ float scrB2[4096];
    __shared__ float sp1s[512], dp1s[512];
    __shared__ float sp2s[512], dp2s[512];
    __shared__ float biasg[128];
    float* hp2 = hp1s;
    float* xn  = scrB2;
    float* x2  = scrB2;

    const int pfrag = lane & 15, kg8 = (lane >> 4) * 8;
    const int lb2 = lane >> 4, u2 = (lane >> 2) & 3, t_ = lane & 3;
    const int j2 = wv * 4 + u2;

    short8_t wfhT[2], wflT[2], wfhG[2], wflG[2];
    {
        int gp = wv * 16 + pfrag, j = gp >> 2, ty = gp & 3, orig = ty * 32 + j;
        #pragma unroll
        for (int kb = 0; kb < 2; ++kb) {
            short8_t fhT, flT, fhG, flG;
            #pragma unroll
            for (int jj = 0; jj < 8; ++jj) {
                int k = kb * 32 + (lane >> 4) * 8 + jj;
                float vT, vG;
                if (k < 32)       vT = w_hh_t[orig * 32 + k];
                else if (k < 35)  vT = w_ih_t[orig * 3 + (k - 32)];
                else if (k == 35) vT = b_ih_t[orig] + b_hh_t[orig];
                else              vT = 0.0f;
                if (k < 32)       vG = w_ih_g[orig * 32 + k];
                else              vG = w_hh_g[orig * 32 + (k - 32)];
                u16 hT = bhi(vT); fhT[jj] = (short)hT; flT[jj] = (short)bhi(vT - bf2f(hT));
                u16 hG = bhi(vG); fhG[jj] = (short)hG; flG[jj] = (short)bhi(vG - bf2f(hG));
            }
            wfhT[kb] = fhT; wflT[kb] = flT;
            wfhG[kb] = fhG; wflG[kb] = flG;
        }
    }
    #pragma unroll
    for (int r = 0; r < 4; ++r) {
        int j = wv * 4 + r;
        float vt = traj_h0[n * HT_ + j];
        u16 ht = bhi(vt);
        ATh[lane * EAP + j] = ht;  ATl[lane * EAP + j] = bhi(vt - bf2f(ht));
        float vg = graph_h0[n * HG_ + j];
        u16 hg = bhi(vg);
        AGh[lane * EAP + 32 + j] = hg;  AGl[lane * EAP + 32 + j] = bhi(vg - bf2f(hg));
    }
    float cT2[4], cG2[4];
    #pragma unroll
    for (int mb = 0; mb < 4; ++mb) {
        int p = mb * 16 + lb2 * 4 + t_;
        cT2[mb] = traj_c0[(g * 64 + p) * HT_ + j2];
        cG2[mb] = graph_c0[(g * 64 + p) * HG_ + j2];
    }
    if (wv == 0) {
        #pragma unroll
        for (int c = 0; c < 3; ++c) {
            float v = obs[(0 * NTOT + n) * 3 + c];
            u16 h = bhi(v);
            ATh[lane * EAP + 32 + c] = h;  ATl[lane * EAP + 32 + c] = bhi(v - bf2f(h));
        }
        ATh[lane * EAP + 35] = 0x3F80;  ATl[lane * EAP + 35] = 0;
    } else if (wv == 1) {
        for (int c = 36; c < 64; ++c) { ATh[lane * EAP + c] = 0; ATl[lane * EAP + c] = 0; }
    }
    if (threadIdx.x < 128) biasg[threadIdx.x] = b_ih_g[threadIdx.x] + b_hh_g[threadIdx.x];
    __syncthreads();

    for (int t = 0; t < OBS; ++t) {
        float h2T[4], xnv[4];
        {
            f32x4 acc[4];
            #pragma unroll
            for (int mb = 0; mb < 4; ++mb) acc[mb] = (f32x4){0.f, 0.f, 0.f, 0.f};
            #pragma unroll
            for (int kb = 0; kb < 2; ++kb) {
                short8_t ah[4], al[4];
                #pragma unroll
                for (int mb = 0; mb < 4; ++mb) {
                    int off = (mb * 16 + pfrag) * EAP + kb * 32 + kg8;
                    ah[mb] = *(const short8_t*)&ATh[off];
                    al[mb] = *(const short8_t*)&ATl[off];
                }
                #pragma unroll
                for (int mb = 0; mb < 4; ++mb) {
                    acc[mb] = __builtin_amdgcn_mfma_f32_16x16x32_bf16(ah[mb], wfhT[kb], acc[mb], 0, 0, 0);
                    acc[mb] = __builtin_amdgcn_mfma_f32_16x16x32_bf16(ah[mb], wflT[kb], acc[mb], 0, 0, 0);
                    acc[mb] = __builtin_amdgcn_mfma_f32_16x16x32_bf16(al[mb], wfhT[kb], acc[mb], 0, 0, 0);
                }
            }
            #pragma unroll
            for (int mb = 0; mb < 4; ++mb)
                xpose_update(acc[mb], lane, 0.f, 0.f, 0.f, 0.f, cT2[mb], h2T[mb]);
            float sm = h2T[0] + h2T[1] + h2T[2] + h2T[3];
            float sq = h2T[0]*h2T[0] + h2T[1]*h2T[1] + h2T[2]*h2T[2] + h2T[3]*h2T[3];
            sm += __shfl_xor(sm, 1);  sq += __shfl_xor(sq, 1);
            sm += __shfl_xor(sm, 2);  sq += __shfl_xor(sq, 2);
            sm += __shfl_xor(sm, 16); sq += __shfl_xor(sq, 16);
            sm += __shfl_xor(sm, 32); sq += __shfl_xor(sq, 32);
            float mean = sm * (1.0f / 64.0f);
            float var  = sq * (1.0f / 64.0f) - mean * mean;
            float rstd = rsqrtf(var + 1e-5f);
            #pragma unroll
            for (int mb = 0; mb < 4; ++mb) xnv[mb] = (h2T[mb] - mean) * rstd;
        }
        __syncthreads();
        #pragma unroll
        for (int mb = 0; mb < 4; ++mb) {
            int p = mb * 16 + lb2 * 4 + t_;
            u16 h = bhi(h2T[mb]);
            ATh[p * EAP + j2] = h;  ATl[p * EAP + j2] = bhi(h2T[mb] - bf2f(h));
            xn[j2 * 64 + p] = xnv[mb];
        }
        if (t == OBS - 1) {
            #pragma unroll
            for (int mb = 0; mb < 4; ++mb) {
                int p = mb * 16 + lb2 * 4 + t_;
                wsT[j2 * NTOT + g * 64 + p] = h2T[mb];
            }
        }
        if (wv == 0 && t < OBS - 1) {
            #pragma unroll
            for (int c = 0; c < 3; ++c) {
                float v = obs[((t + 1) * NTOT + n) * 3 + c];
                u16 h = bhi(v);
                ATh[lane * EAP + 32 + c] = h;  ATl[lane * EAP + 32 + c] = bhi(v - bf2f(h));
            }
        }
        __syncthreads();
        {
            const int h_ = wv >> 1;
            const int o0 = (wv & 1) * 8;
            float acc[8];
            #pragma unroll
            for (int q = 0; q < 8; ++q) acc[q] = 0.0f;
            for (int k8 = 0; k8 < 4; ++k8) {
                float xk[8];
                #pragma unroll
                for (int i = 0; i < 8; ++i) xk[i] = xn[(k8 * 8 + i) * 64 + lane];
                #pragma unroll
                for (int i = 0; i < 8; ++i)
                    #pragma unroll
                    for (int q = 0; q < 8; ++q)
                        acc[q] += g1w[h_ * 512 + (k8 * 8 + i) * 16 + o0 + q] * xk[i];
            }
            float ps = 0.0f, pd = 0.0f;
            #pragma unroll
            for (int q = 0; q < 8; ++q) {
                hp1s[(h_ * 16 + o0 + q) * 64 + lane] = acc[q];
                ps += acc[q] * g1as[h_ * 16 + o0 + q];
                pd += acc[q] * g1ad[h_ * 16 + o0 + q];
            }
            sp1s[((wv & 1) * 4 + h_) * 64 + lane] = ps;
            dp1s[((wv & 1) * 4 + h_) * 64 + lane] = pd;
        }
        __syncthreads();
        {
            const int h_ = wv >> 1;
            const int o0 = (wv & 1) * 8;
            const float sv   = sp1s[h_ * 64 + lane] + sp1s[(4 + h_) * 64 + lane];
            const float dtot = dp1s[h_ * 64 + lane] + dp1s[(4 + h_) * 64 + lane];
            float sum = 0.0f;
            float acc[8];
            #pragma unroll
            for (int q = 0; q < 8; ++q) acc[q] = 0.0f;
            #pragma unroll
            for (int m4 = 0; m4 < 16; ++m4) {
                float e0 = __expf(leaky(sv + __shfl(dtot, m4 * 4 + 0)));
                float e1 = __expf(leaky(sv + __shfl(dtot, m4 * 4 + 1)));
                float e2 = __expf(leaky(sv + __shfl(dtot, m4 * 4 + 2)));
                float e3 = __expf(leaky(sv + __shfl(dtot, m4 * 4 + 3)));
                sum += e0 + e1 + e2 + e3;
                #pragma unroll
                for (int q = 0; q < 8; ++q) {
                    float4 hv = *reinterpret_cast<const float4*>(&hp1s[(h_ * 16 + o0 + q) * 64 + m4 * 4]);
                    acc[q] += e0 * hv.x + e1 * hv.y + e2 * hv.z + e3 * hv.w;
                }
            }
            float rs = 1.0f / sum;
            #pragma unroll
            for (int q = 0; q < 8; ++q) {
                float v = acc[q] * rs + g1b[o0 + q];
                v = (v > 0.0f) ? v : (__expf(v) - 1.0f);
                float sm = v, sq = v * v;
                #pragma unroll
                for (int m = 1; m < 64; m <<= 1) { sm += __shfl_xor(sm, m); sq += __shfl_xor(sq, m); }
                float mean = sm * (1.0f / 64.0f);
                float var  = sq * (1.0f / 64.0f) - mean * mean;
                x2[(h_ * 16 + o0 + q) * 64 + lane] = (v - mean) * rsqrtf(var + 1e-5f);
            }
        }
        __syncthreads();
        {
            float acc[4];
            #pragma unroll
            for (int q = 0; q < 4; ++q) acc[q] = 0.0f;
            for (int k8 = 0; k8 < 8; ++k8) {
                float xk[8];
                #pragma unroll
                for (int i = 0; i < 8; ++i) xk[i] = x2[(k8 * 8 + i) * 64 + lane];
                #pragma unroll
                for (int i = 0; i < 8; ++i)
                    #pragma unroll
                    for (int q = 0; q < 4; ++q)
                        acc[q] += g2w[(k8 * 8 + i) * 32 + wv * 4 + q] * xk[i];
            }
            float ps = 0.0f, pd = 0.0f;
            #pragma unroll
            for (int q = 0; q < 4; ++q) {
                hp2[(wv * 4 + q) * 64 + lane] = acc[q];
                ps += acc[q] * g2as[wv * 4 + q];
                pd += acc[q] * g2ad[wv * 4 + q];
            }
            sp2s[wv * 64 + lane] = ps;
            dp2s[wv * 64 + lane] = pd;
        }
        __syncthreads();
        {
            float sv = 0.0f, dtot = 0.0f;
            #pragma unroll
            for (int w = 0; w < 8; ++w) { sv += sp2s[w * 64 + lane]; dtot += dp2s[w * 64 + lane]; }
            float sum = 0.0f;
            float acc[4];
            #pragma unroll
            for (int q = 0; q < 4; ++q) acc[q] = 0.0f;
            #pragma unroll
            for (int m4 = 0; m4 < 16; ++m4) {
                float e0 = __expf(leaky(sv + __shfl(dtot, m4 * 4 + 0)));
                float e1 = __expf(leaky(sv + __shfl(dtot, m4 * 4 + 1)));
                float e2 = __expf(leaky(sv + __shfl(dtot, m4 * 4 + 2)));
                float e3 = __expf(leaky(sv + __shfl(dtot, m4 * 4 + 3)));
                sum += e0 + e1 + e2 + e3;
                #pragma unroll
                for (int q = 0; q < 4; ++q) {
                    float4 hv = *reinterpret_cast<const float4*>(&hp2[(wv * 4 + q) * 64 + m4 * 4]);
                    acc[q] += e0 * hv.x + e1 * hv.y + e2 * hv.z + e3 * hv.w;
                }
            }
            float rs = 1.0f / sum;
            #pragma unroll
            for (int q = 0; q < 4; ++q) {
                float v = acc[q] * rs + g2b[wv * 4 + q];
                u16 h = bhi(v);
                AGh[lane * EAP + wv * 4 + q] = h;
                AGl[lane * EAP + wv * 4 + q] = bhi(v - bf2f(h));
            }
        }
        __syncthreads();
        float h2G[4];
        {
            f32x4 acc[4];
            #pragma unroll
            for (int mb = 0; mb < 4; ++mb) acc[mb] = (f32x4){0.f, 0.f, 0.f, 0.f};
            #pragma unroll
            for (int kb = 0; kb < 2; ++kb) {
                short8_t ah[4], al[4];
                #pragma unroll
                for (int mb = 0; mb < 4; ++mb) {
                    int off = (mb * 16 + pfrag) * EAP + kb * 32 + kg8;
                    ah[mb] = *(const short8_t*)&AGh[off];
                    al[mb] = *(const short8_t*)&AGl[off];
                }
                #pragma unroll
                for (int mb = 0; mb < 4; ++mb) {
                    acc[mb] = __builtin_amdgcn_mfma_f32_16x16x32_bf16(ah[mb], wfhG[kb], acc[mb], 0, 0, 0);
                    acc[mb] = __builtin_amdgcn_mfma_f32_16x16x32_bf16(ah[mb], wflG[kb], acc[mb], 0, 0, 0);
                    acc[mb] = __builtin_amdgcn_mfma_f32_16x16x32_bf16(al[mb], wfhG[kb], acc[mb], 0, 0, 0);
                }
            }
            const float bI = biasg[j2], bF = biasg[32 + j2], bG = biasg[64 + j2], bO = biasg[96 + j2];
            #pragma unroll
            for (int mb = 0; mb < 4; ++mb)
                xpose_update(acc[mb], lane, bI, bF, bG, bO, cG2[mb], h2G[mb]);
        }
        __syncthreads();
        #pragma unroll
        for (int mb = 0; mb < 4; ++mb) {
            int p = mb * 16 + lb2 * 4 + t_;
            u16 h = bhi(h2G[mb]);
            AGh[p * EAP + 32 + j2] = h;  AGl[p * EAP + 32 + j2] = bhi(h2G[mb] - bf2f(h));
        }
        if (t == OBS - 1) {
            #pragma unroll
            for (int mb = 0; mb < 4; ++mb) {
                int p = mb * 16 + lb2 * 4 + t_;
                wsG[j2 * NTOT + g * 64 + p] = h2G[mb];
            }
        }
    }
}

// ====================== D: decoder (B3 removed) ===========================
__global__ __launch_bounds__(512, 1)
void stgat_dec(const float* __restrict__ obs,
               const float* __restrict__ zin,
               const float* __restrict__ w_ih_p,
               const float* __restrict__ w_hh_p,
               const float* __restrict__ b_ih_p,
               const float* __restrict__ b_hh_p,
               const float* __restrict__ w_out,
               const float* __restrict__ b_out,
               const float* __restrict__ wsT,
               const float* __restrict__ wsG,
               float* __restrict__ out)
{
    const int g    = blockIdx.x;
    const int lane = threadIdx.x & 63;
    const int wv   = __builtin_amdgcn_readfirstlane((int)(threadIdx.x >> 6));
    const int n    = g * NPED + lane;

    __shared__ __attribute__((aligned(16))) u16 Apack[4 * 64 * AP];
    __shared__ __attribute__((aligned(16))) short8_t WloS[18 * 3 * 64];
    u16* AhiA = Apack;
    u16* AloA = AhiA + 64 * AP;
    u16* AhiB = AloA + 64 * AP;
    u16* AloB = AhiB + 64 * AP;

    short8_t wfh[3][3];
    {
        const int col = lane & 15, lb = lane >> 4;
        #pragma unroll
        for (int s = 0; s < 3; ++s) {
            if (s < 2 || wv < 2) {
                int nb = wv + 8 * s;
                int gp = nb * 16 + col;
                int j = gp >> 2, ty = gp & 3;
                int orig = ty * HP_ + j;
                #pragma unroll
                for (int kb = 0; kb < 3; ++kb) {
                    short8_t fh, fl;
                    #pragma unroll
                    for (int jj = 0; jj < 8; ++jj) {
                        int k = kb * 32 + lb * 8 + jj;
                        float v;
                        if (k < 72)       v = w_hh_p[orig * HP_ + k];
                        else if (k == 72) v = w_ih_p[orig * 2 + 0];
                        else if (k == 73) v = w_ih_p[orig * 2 + 1];
                        else if (k == 74) v = b_ih_p[orig] + b_hh_p[orig];
                        else              v = 0.0f;
                        u16 hb = bhi(v);
                        fh[jj] = (short)hb;
                        fl[jj] = (short)bhi(v - bf2f(hb));
                    }
                    wfh[s][kb] = fh;
                    WloS[(nb * 3 + kb) * 64 + lane] = fl;
                }
            }
        }
    }
    {
        float px0 = obs[(7 * NTOT + n) * 3 + 0];
        float px1 = obs[(7 * NTOT + n) * 3 + 1];
        #pragma unroll
        for (int kk = 0; kk < 12; ++kk) {
            int k = wv + kk * 8;
            float va, vb;
            if (k < 32)       { va = wsT[(size_t)k * NTOT + n];            vb = 0.0f; }
            else if (k < 64)  { va = vb = wsG[(size_t)(k - 32) * NTOT + n]; }
            else if (k < 72)  { va = vb = zin[g * NZ_ + (k - 64)]; }
            else if (k == 72) { va = vb = px0; }
            else if (k == 73) { va = vb = px1; }
            else if (k == 74) { va = vb = 1.0f; }
            else              { va = vb = 0.0f; }
            u16 ha = bhi(va); u16 la = bhi(va - bf2f(ha));
            u16 hb = bhi(vb); u16 lb_ = bhi(vb - bf2f(hb));
            AhiA[lane * AP + k] = ha;  AloA[lane * AP + k] = la;
            AhiB[lane * AP + k] = hb;  AloB[lane * AP + k] = lb_;
        }
    }
    __syncthreads();

    float cstA[3][4], cstB[3][4];
    #pragma unroll
    for (int s = 0; s < 3; ++s)
        #pragma unroll
        for (int mb = 0; mb < 4; ++mb) { cstA[s][mb] = 0.0f; cstB[s][mb] = 0.0f; }

    const int lb2 = lane >> 4, u_ = (lane >> 2) & 3, t_ = lane & 3;
    const int pfrag = lane & 15, kgrp = (lane >> 4) * 8;

    for (int st = 0; st < FUT; ++st) {
        float h2A[3][4], h2B[3][4];
        {
            f32x4 acc[3][4];
            #pragma unroll
            for (int s = 0; s < 3; ++s)
                #pragma unroll
                for (int mb = 0; mb < 4; ++mb) acc[s][mb] = (f32x4){0.f, 0.f, 0.f, 0.f};
            #pragma unroll
            for (int kb = 0; kb < 3; ++kb) {
                short8_t ah[4], al[4];
                #pragma unroll
                for (int mb = 0; mb < 4; ++mb) {
                    int off = (mb * 16 + pfrag) * AP + kb * 32 + kgrp;
                    ah[mb] = *(const short8_t*)&AhiA[off];
                    al[mb] = *(const short8_t*)&AloA[off];
                }
                #pragma unroll
                for (int s = 0; s < 3; ++s) {
                    if (s < 2 || wv < 2) {
                        int nb = wv + 8 * s;
                        short8_t wl = WloS[(nb * 3 + kb) * 64 + lane];
                        #pragma unroll
                        for (int mb = 0; mb < 4; ++mb) {
                            acc[s][mb] = __builtin_amdgcn_mfma_f32_16x16x32_bf16(ah[mb], wfh[s][kb], acc[s][mb], 0, 0, 0);
                            acc[s][mb] = __builtin_amdgcn_mfma_f32_16x16x32_bf16(ah[mb], wl,         acc[s][mb], 0, 0, 0);
                            acc[s][mb] = __builtin_amdgcn_mfma_f32_16x16x32_bf16(al[mb], wfh[s][kb], acc[s][mb], 0, 0, 0);
                        }
                    }
                }
            }
            #pragma unroll
            for (int s = 0; s < 3; ++s)
                #pragma unroll
                for (int mb = 0; mb < 4; ++mb)
                    xpose_update(acc[s][mb], lane, 0.f, 0.f, 0.f, 0.f, cstA[s][mb], h2A[s][mb]);
        }
        {
            f32x4 acc[3][4];
            #pragma unroll
            for (int s = 0; s < 3; ++s)
                #pragma unroll
                for (int mb = 0; mb < 4; ++mb) acc[s][mb] = (f32x4){0.f, 0.f, 0.f, 0.f};
            #pragma unroll
            for (int kb = 0; kb < 3; ++kb) {
                short8_t bh[4], bl[4];
                #pragma unroll
                for (int mb = 0; mb < 4; ++mb) {
                    int off = (mb * 16 + pfrag) * AP + kb * 32 + kgrp;
                    bh[mb] = *(const short8_t*)&AhiB[off];
                    bl[mb] = *(const short8_t*)&AloB[off];
                }
                #pragma unroll
                for (int s = 0; s < 3; ++s) {
                    if (s < 2 || wv < 2) {
                        int nb = wv + 8 * s;
                        short8_t wl = WloS[(nb * 3 + kb) * 64 + lane];
                        #pragma unroll
                        for (int mb = 0; mb < 4; ++mb) {
                            acc[s][mb] = __builtin_amdgcn_mfma_f32_16x16x32_bf16(bh[mb], wfh[s][kb], acc[s][mb], 0, 0, 0);
                            acc[s][mb] = __builtin_amdgcn_mfma_f32_16x16x32_bf16(bh[mb], wl,         acc[s][mb], 0, 0, 0);
                            acc[s][mb] = __builtin_amdgcn_mfma_f32_16x16x32_bf16(bl[mb], wfh[s][kb], acc[s][mb], 0, 0, 0);
                        }
                    }
                }
            }
            #pragma unroll
            for (int s = 0; s < 3; ++s)
                #pragma unroll
                for (int mb = 0; mb < 4; ++mb)
                    xpose_update(acc[s][mb], lane, 0.f, 0.f, 0.f, 0.f, cstB[s][mb], h2B[s][mb]);
        }
        __syncthreads();   // B1: GEMM reads done
        #pragma unroll
        for (int s = 0; s < 3; ++s) {
            if (s < 2 || wv < 2) {
                int nb = wv + 8 * s;
                int j = nb * 4 + u_;
                #pragma unroll
                for (int mb = 0; mb < 4; ++mb) {
                    int p = mb * 16 + lb2 * 4 + t_;
                    float va = h2A[s][mb];
                    float vb = h2B[s][mb];
                    u16 ha = bhi(va);
                    AhiA[p * AP + j] = ha;  AloA[p * AP + j] = bhi(va - bf2f(ha));
                    u16 hb = bhi(vb);
                    AhiB[p * AP + j] = hb;  AloB[p * AP + j] = bhi(vb - bf2f(hb));
                }
            }
        }
        __syncthreads();   // B2: h2 published
        // all waves redundantly compute output dot (identical values) -> no B3
        {
            float s0 = 0.0f, s1_ = 0.0f;
            #pragma unroll
            for (int jb = 0; jb < 9; ++jb) {
                short8_t xha = *(const short8_t*)&AhiA[lane * AP + jb * 8];
                short8_t xla = *(const short8_t*)&AloA[lane * AP + jb * 8];
                short8_t xhb = *(const short8_t*)&AhiB[lane * AP + jb * 8];
                short8_t xlb = *(const short8_t*)&AloB[lane * AP + jb * 8];
                #pragma unroll
                for (int jj = 0; jj < 8; ++jj) {
                    int j = jb * 8 + jj;
                    float dh = (bf2f((u16)xha[jj]) + bf2f((u16)xla[jj]))
                             - (bf2f((u16)xhb[jj]) + bf2f((u16)xlb[jj]));
                    s0  += w_out[j] * dh;
                    s1_ += w_out[HP_ + j] * dh;
                }
            }
            float o0 = s0 + b_out[0], o1 = s1_ + b_out[1];
            if (wv == 0)
                *reinterpret_cast<float2*>(&out[(size_t)(st * NTOT + n) * 2]) = make_float2(o0, o1);
            u16 h0_ = bhi(o0); u16 l0 = bhi(o0 - bf2f(h0_));
            u16 h1 = bhi(o1); u16 l1 = bhi(o1 - bf2f(h1));
            AhiA[lane * AP + 72] = h0_;  AloA[lane * AP + 72] = l0;
            AhiB[lane * AP + 72] = h0_;  AloB[lane * AP + 72] = l0;
            AhiA[lane * AP + 73] = h1;   AloA[lane * AP + 73] = l1;
            AhiB[lane * AP + 73] = h1;   AloB[lane * AP + 73] = l1;
        }
    }
}

extern "C" void kernel_launch(void* const* d_in, const int* in_sizes, int n_in,
                              void* d_out, int out_size, void* d_ws, size_t ws_size,
                              hipStream_t stream) {
    (void)in_sizes; (void)n_in; (void)out_size;
    const size_t NF  = (size_t)OBS * 32 * NTOT;        // 16.78M floats
    const size_t REQ = 2 * NF * 4 + 2 * (size_t)32 * NTOT * 4;   // ws1+ws2+wsT+wsG ≈ 151MB

    if (ws_size >= REQ) {
        float* ws1 = (float*)d_ws;
        float* ws2 = ws1 + NF;
        float* wsT = ws2 + NF;
        float* wsG = wsT + (size_t)32 * NTOT;

        traj_lstm_k<<<dim3(NTOT / 256), dim3(256), 0, stream>>>(
            (const float*)d_in[0], (const float*)d_in[2], (const float*)d_in[3],
            (const float*)d_in[6], (const float*)d_in[7], (const float*)d_in[8], (const float*)d_in[9],
            ws1, wsT);

        gat_k<<<dim3(OBS * NGR), dim3(512), 0, stream>>>(
            ws1,
            (const float*)d_in[10], (const float*)d_in[11], (const float*)d_in[12], (const float*)d_in[13],
            (const float*)d_in[14], (const float*)d_in[15], (const float*)d_in[16], (const float*)d_in[17],
            ws2);

        graph_lstm_k<<<dim3(NGR), dim3(512), 0, stream>>>(
            ws2, (const float*)d_in[4], (const float*)d_in[5],
            (const float*)d_in[18], (const float*)d_in[19], (const float*)d_in[20], (const float*)d_in[21],
            wsG);

        stgat_dec<<<dim3(NGR), dim3(512), 0, stream>>>(
            (const float*)d_in[0], (const float*)d_in[1],
            (const float*)d_in[22], (const float*)d_in[23],
            (const float*)d_in[24], (const float*)d_in[25],
            (const float*)d_in[26], (const float*)d_in[27],
            wsT, wsG, (float*)d_out);
    } else {
        float* wsT = (float*)d_ws;
        float* wsG = wsT + (size_t)HT_ * NTOT;
        stgat_enc<<<dim3(NGR), dim3(512), 0, stream>>>(
            (const float*)d_in[0],
            (const float*)d_in[2],  (const float*)d_in[3],
            (const float*)d_in[4],  (const float*)d_in[5],
            (const float*)d_in[6],  (const float*)d_in[7],  (const float*)d_in[8],  (const float*)d_in[9],
            (const float*)d_in[10], (const float*)d_in[11], (const float*)d_in[12], (const float*)d_in[13],
            (const float*)d_in[14], (const float*)d_in[15], (const float*)d_in[16], (const float*)d_in[17],
            (const float*)d_in[18], (const float*)d_in[19], (const float*)d_in[20], (const float*)d_in[21],
            wsT, wsG);
        stgat_dec<<<dim3(NGR), dim3(512), 0, stream>>>(
            (const float*)d_in[0], (const float*)d_in[1],
            (const float*)d_in[22], (const float*)d_in[23],
            (const float*)d_in[24], (const float*)d_in[25],
            (const float*)d_in[26], (const float*)d_in[27],
            wsT, wsG, (float*)d_out);
    }
}

// Round 9
// 1279.282 us; speedup vs baseline: 1.1848x; 1.1534x over previous
//
#include <hip/hip_runtime.h>

// STGAT round 9: decoder MFMA operand-swap (C = [gate'][ped], reg idx = gate
// type -> NO shuffle-transpose) + register-resident output dot (no redundant
// LDS dot; 3 barriers/step). Same swap in graph_lstm_k. traj/gat unchanged.

#define OBS 8
#define FUT 12
#define NPED 64
#define HT_ 32
#define HG_ 32
#define NZ_ 8
#define HP_ 72
#define NGR 1024
#define NTOT (NGR * NPED)
#define AP 104
#define EAP 72

typedef __attribute__((ext_vector_type(8))) short short8_t;
typedef __attribute__((ext_vector_type(4))) float f32x4;
typedef unsigned short u16;

__device__ __forceinline__ float sigf(float x) { return 1.0f / (1.0f + __expf(-x)); }
__device__ __forceinline__ float tanh_(float x) {
    float e = __expf(2.0f * x);
    return 1.0f - 2.0f / (e + 1.0f);
}
__device__ __forceinline__ float leaky(float x) { return (x > 0.0f) ? x : 0.2f * x; }
__device__ __forceinline__ u16 bhi(float v) {
    unsigned u = __float_as_uint(v);
    return (u16)((u + 0x7FFFu + ((u >> 16) & 1u)) >> 16);
}
__device__ __forceinline__ float bf2f(u16 h) { return __uint_as_float(((unsigned)h) << 16); }

// ====================== A: traj LSTM (no barriers) ========================
__global__ __launch_bounds__(256, 1)
void traj_lstm_k(const float* __restrict__ obs,
                 const float* __restrict__ h0,
                 const float* __restrict__ c0,
                 const float* __restrict__ w_ih,
                 const float* __restrict__ w_hh,
                 const float* __restrict__ b_ih,
                 const float* __restrict__ b_hh,
                 float* __restrict__ ws1,    // xn f32 [8][32][N]
                 float* __restrict__ wsT)    // raw h at t=7, [32][N]
{
    const int tid = threadIdx.x;
    const int n   = blockIdx.x * 256 + tid;
    __shared__ __attribute__((aligned(16))) float W[128 * 36];
    __shared__ float hc[256 * 33 * 2];
    float* hl = &hc[tid * 33];
    float* cl = &hc[(256 + tid) * 33];

    for (int i = tid; i < 128 * 36; i += 256) {
        int gate = i / 36, k = i - gate * 36;
        float v;
        if (k < 32)      v = w_hh[gate * 32 + k];
        else if (k < 35) v = w_ih[gate * 3 + (k - 32)];
        else             v = b_ih[gate] + b_hh[gate];
        W[i] = v;
    }
    #pragma unroll
    for (int j4 = 0; j4 < 8; ++j4) {
        f32x4 hv = *(const f32x4*)&h0[(size_t)n * 32 + j4 * 4];
        f32x4 cv = *(const f32x4*)&c0[(size_t)n * 32 + j4 * 4];
        #pragma unroll
        for (int r = 0; r < 4; ++r) { hl[j4 * 4 + r] = hv[r]; cl[j4 * 4 + r] = cv[r]; }
    }
    __syncthreads();

    for (int t = 0; t < OBS; ++t) {
        f32x4 v4[9];
        #pragma unroll
        for (int kq = 0; kq < 8; ++kq) {
            f32x4 x;
            #pragma unroll
            for (int r = 0; r < 4; ++r) x[r] = hl[kq * 4 + r];
            v4[kq] = x;
        }
        {
            const float* ob = &obs[((size_t)t * NTOT + n) * 3];
            v4[8] = (f32x4){ob[0], ob[1], ob[2], 1.0f};
        }
        #pragma unroll 4
        for (int j = 0; j < 32; ++j) {
            f32x4 ai = {0,0,0,0}, af4 = {0,0,0,0}, ag4 = {0,0,0,0}, ao4 = {0,0,0,0};
            #pragma unroll
            for (int kq = 0; kq < 9; ++kq) {
                ai  += *(const f32x4*)&W[(j)      * 36 + kq * 4] * v4[kq];
                af4 += *(const f32x4*)&W[(32 + j) * 36 + kq * 4] * v4[kq];
                ag4 += *(const f32x4*)&W[(64 + j) * 36 + kq * 4] * v4[kq];
                ao4 += *(const f32x4*)&W[(96 + j) * 36 + kq * 4] * v4[kq];
            }
            float gi = (ai[0]  + ai[1])  + (ai[2]  + ai[3]);
            float gf = (af4[0] + af4[1]) + (af4[2] + af4[3]);
            float gg = (ag4[0] + ag4[1]) + (ag4[2] + ag4[3]);
            float go = (ao4[0] + ao4[1]) + (ao4[2] + ao4[3]);
            float cc = sigf(gf) * cl[j] + sigf(gi) * tanh_(gg);
            cl[j] = cc;
            hl[j] = sigf(go) * tanh_(cc);
        }
        #pragma unroll 4
        for (int f = 0; f < 32; ++f) {
            float v = hl[f];
            float sm = v, sq = v * v;
            #pragma unroll
            for (int m = 1; m < 64; m <<= 1) { sm += __shfl_xor(sm, m); sq += __shfl_xor(sq, m); }
            float mean = sm * (1.0f / 64.0f);
            float var  = sq * (1.0f / 64.0f) - mean * mean;
            ws1[((size_t)t * 32 + f) * NTOT + n] = (v - mean) * rsqrtf(var + 1e-5f);
        }
        if (t == OBS - 1) {
            #pragma unroll 4
            for (int f = 0; f < 32; ++f) wsT[(size_t)f * NTOT + n] = hl[f];
        }
    }
}

// ====================== B: GAT, one block per (t,g) =======================
__global__ __launch_bounds__(512, 2)
void gat_k(const float* __restrict__ ws1,
           const float* __restrict__ g1w,
           const float* __restrict__ g1as,
           const float* __restrict__ g1ad,
           const float* __restrict__ g1b,
           const float* __restrict__ g2w,
           const float* __restrict__ g2as,
           const float* __restrict__ g2ad,
           const float* __restrict__ g2b,
           float* __restrict__ ws2)
{
    const int t    = blockIdx.x >> 10;
    const int g    = blockIdx.x & 1023;
    const int lane = threadIdx.x & 63;
    const int wv   = __builtin_amdgcn_readfirstlane((int)(threadIdx.x >> 6));

    __shared__ float hp1s[4096];
    __shared__ float xnx[4096];
    __shared__ float sp1s[512], dp1s[512], sp2s[512], dp2s[512];
    float* xn  = xnx;
    float* x2  = xnx;
    float* hp2 = hp1s;

    #pragma unroll
    for (int r = 0; r < 4; ++r) {
        int f = wv * 4 + r;
        xn[f * 64 + lane] = ws1[((size_t)t * 32 + f) * NTOT + g * 64 + lane];
    }
    __syncthreads();
    {
        const int h_ = wv >> 1;
        const int o0 = (wv & 1) * 8;
        float acc[8];
        #pragma unroll
        for (int q = 0; q < 8; ++q) acc[q] = 0.0f;
        for (int k8 = 0; k8 < 4; ++k8) {
            float xk[8];
            #pragma unroll
            for (int i = 0; i < 8; ++i) xk[i] = xn[(k8 * 8 + i) * 64 + lane];
            #pragma unroll
            for (int i = 0; i < 8; ++i)
                #pragma unroll
                for (int q = 0; q < 8; ++q)
                    acc[q] += g1w[h_ * 512 + (k8 * 8 + i) * 16 + o0 + q] * xk[i];
        }
        float ps = 0.0f, pd = 0.0f;
        #pragma unroll
        for (int q = 0; q < 8; ++q) {
            hp1s[(h_ * 16 + o0 + q) * 64 + lane] = acc[q];
            ps += acc[q] * g1as[h_ * 16 + o0 + q];
            pd += acc[q] * g1ad[h_ * 16 + o0 + q];
        }
        sp1s[((wv & 1) * 4 + h_) * 64 + lane] = ps;
        dp1s[((wv & 1) * 4 + h_) * 64 + lane] = pd;
    }
    __syncthreads();
    {
        const int h_ = wv >> 1;
        const int o0 = (wv & 1) * 8;
        const float sv   = sp1s[h_ * 64 + lane] + sp1s[(4 + h_) * 64 + lane];
        const float dtot = dp1s[h_ * 64 + lane] + dp1s[(4 + h_) * 64 + lane];
        float sum = 0.0f;
        float acc[8];
        #pragma unroll
        for (int q = 0; q < 8; ++q) acc[q] = 0.0f;
        #pragma unroll
        for (int m4 = 0; m4 < 16; ++m4) {
            float e0 = __expf(leaky(sv + __shfl(dtot, m4 * 4 + 0)));
            float e1 = __expf(leaky(sv + __shfl(dtot, m4 * 4 + 1)));
            float e2 = __expf(leaky(sv + __shfl(dtot, m4 * 4 + 2)));
            float e3 = __expf(leaky(sv + __shfl(dtot, m4 * 4 + 3)));
            sum += e0 + e1 + e2 + e3;
            #pragma unroll
            for (int q = 0; q < 8; ++q) {
                float4 hv = *reinterpret_cast<const float4*>(&hp1s[(h_ * 16 + o0 + q) * 64 + m4 * 4]);
                acc[q] += e0 * hv.x + e1 * hv.y + e2 * hv.z + e3 * hv.w;
            }
        }
        float rs = 1.0f / sum;
        #pragma unroll
        for (int q = 0; q < 8; ++q) {
            float v = acc[q] * rs + g1b[o0 + q];
            v = (v > 0.0f) ? v : (__expf(v) - 1.0f);
            float sm = v, sq = v * v;
            #pragma unroll
            for (int m = 1; m < 64; m <<= 1) { sm += __shfl_xor(sm, m); sq += __shfl_xor(sq, m); }
            float mean = sm * (1.0f / 64.0f);
            float var  = sq * (1.0f / 64.0f) - mean * mean;
            x2[(h_ * 16 + o0 + q) * 64 + lane] = (v - mean) * rsqrtf(var + 1e-5f);
        }
    }
    __syncthreads();
    {
        float acc[4];
        #pragma unroll
        for (int q = 0; q < 4; ++q) acc[q] = 0.0f;
        for (int k8 = 0; k8 < 8; ++k8) {
            float xk[8];
            #pragma unroll
            for (int i = 0; i < 8; ++i) xk[i] = x2[(k8 * 8 + i) * 64 + lane];
            #pragma unroll
            for (int i = 0; i < 8; ++i)
                #pragma unroll
                for (int q = 0; q < 4; ++q)
                    acc[q] += g2w[(k8 * 8 + i) * 32 + wv * 4 + q] * xk[i];
        }
        float ps = 0.0f, pd = 0.0f;
        #pragma unroll
        for (int q = 0; q < 4; ++q) {
            hp2[(wv * 4 + q) * 64 + lane] = acc[q];
            ps += acc[q] * g2as[wv * 4 + q];
            pd += acc[q] * g2ad[wv * 4 + q];
        }
        sp2s[wv * 64 + lane] = ps;
        dp2s[wv * 64 + lane] = pd;
    }
    __syncthreads();
    {
        float sv = 0.0f, dtot = 0.0f;
        #pragma unroll
        for (int w = 0; w < 8; ++w) { sv += sp2s[w * 64 + lane]; dtot += dp2s[w * 64 + lane]; }
        float sum = 0.0f;
        float acc[4];
        #pragma unroll
        for (int q = 0; q < 4; ++q) acc[q] = 0.0f;
        #pragma unroll
        for (int m4 = 0; m4 < 16; ++m4) {
            float e0 = __expf(leaky(sv + __shfl(dtot, m4 * 4 + 0)));
            float e1 = __expf(leaky(sv + __shfl(dtot, m4 * 4 + 1)));
            float e2 = __expf(leaky(sv + __shfl(dtot, m4 * 4 + 2)));
            float e3 = __expf(leaky(sv + __shfl(dtot, m4 * 4 + 3)));
            sum += e0 + e1 + e2 + e3;
            #pragma unroll
            for (int q = 0; q < 4; ++q) {
                float4 hv = *reinterpret_cast<const float4*>(&hp2[(wv * 4 + q) * 64 + m4 * 4]);
                acc[q] += e0 * hv.x + e1 * hv.y + e2 * hv.z + e3 * hv.w;
            }
        }
        float rs = 1.0f / sum;
        #pragma unroll
        for (int q = 0; q < 4; ++q)
            ws2[((size_t)t * 32 + wv * 4 + q) * NTOT + g * 64 + lane] = acc[q] * rs + g2b[wv * 4 + q];
    }
}

// ====================== C: graph LSTM (MFMA, operand-swapped) =============
__global__ __launch_bounds__(512, 1)
void graph_lstm_k(const float* __restrict__ ws2,
                  const float* __restrict__ graph_h0,
                  const float* __restrict__ graph_c0,
                  const float* __restrict__ w_ih_g,
                  const float* __restrict__ w_hh_g,
                  const float* __restrict__ b_ih_g,
                  const float* __restrict__ b_hh_g,
                  float* __restrict__ wsG)
{
    const int g    = blockIdx.x;
    const int lane = threadIdx.x & 63;
    const int wv   = __builtin_amdgcn_readfirstlane((int)(threadIdx.x >> 6));
    const int n    = g * NPED + lane;

    __shared__ __attribute__((aligned(16))) u16 AGh[64 * EAP], AGl[64 * EAP];
    __shared__ float biasg[128];

    const int pfrag = lane & 15, kg8 = (lane >> 4) * 8;
    const int pcol = lane & 15;
    const int jg   = wv * 4 + (lane >> 4);   // owned hidden index after swap

    short8_t wfhG[2], wflG[2];
    {
        int gp = wv * 16 + pfrag, j = gp >> 2, ty = gp & 3, orig = ty * 32 + j;
        #pragma unroll
        for (int kb = 0; kb < 2; ++kb) {
            short8_t fhG, flG;
            #pragma unroll
            for (int jj = 0; jj < 8; ++jj) {
                int k = kb * 32 + (lane >> 4) * 8 + jj;
                float vG = (k < 32) ? w_ih_g[orig * 32 + k] : w_hh_g[orig * 32 + (k - 32)];
                u16 hG = bhi(vG); fhG[jj] = (short)hG; flG[jj] = (short)bhi(vG - bf2f(hG));
            }
            wfhG[kb] = fhG; wflG[kb] = flG;
        }
    }
    #pragma unroll
    for (int r = 0; r < 4; ++r) {
        int j = wv * 4 + r;
        float vg = graph_h0[(size_t)n * HG_ + j];
        u16 hg = bhi(vg);
        AGh[lane * EAP + 32 + j] = hg;  AGl[lane * EAP + 32 + j] = bhi(vg - bf2f(hg));
    }
    float cG2[4];
    #pragma unroll
    for (int mb = 0; mb < 4; ++mb)
        cG2[mb] = graph_c0[(size_t)(g * 64 + mb * 16 + pcol) * HG_ + jg];
    if (threadIdx.x < 128) biasg[threadIdx.x] = b_ih_g[threadIdx.x] + b_hh_g[threadIdx.x];

    for (int t = 0; t < OBS; ++t) {
        #pragma unroll
        for (int r = 0; r < 4; ++r) {
            int f = wv * 4 + r;
            float v = ws2[((size_t)t * 32 + f) * NTOT + g * 64 + lane];
            u16 h = bhi(v);
            AGh[lane * EAP + f] = h;  AGl[lane * EAP + f] = bhi(v - bf2f(h));
        }
        __syncthreads();   // B1
        float h2G[4];
        {
            f32x4 acc[4];
            #pragma unroll
            for (int mb = 0; mb < 4; ++mb) acc[mb] = (f32x4){0.f, 0.f, 0.f, 0.f};
            #pragma unroll
            for (int kb = 0; kb < 2; ++kb) {
                short8_t ah[4], al[4];
                #pragma unroll
                for (int mb = 0; mb < 4; ++mb) {
                    int off = (mb * 16 + pfrag) * EAP + kb * 32 + kg8;
                    ah[mb] = *(const short8_t*)&AGh[off];
                    al[mb] = *(const short8_t*)&AGl[off];
                }
                #pragma unroll
                for (int mb = 0; mb < 4; ++mb) {
                    acc[mb] = __builtin_amdgcn_mfma_f32_16x16x32_bf16(wfhG[kb], ah[mb], acc[mb], 0, 0, 0);
                    acc[mb] = __builtin_amdgcn_mfma_f32_16x16x32_bf16(wflG[kb], ah[mb], acc[mb], 0, 0, 0);
                    acc[mb] = __builtin_amdgcn_mfma_f32_16x16x32_bf16(wfhG[kb], al[mb], acc[mb], 0, 0, 0);
                }
            }
            const float bI = biasg[jg], bF = biasg[32 + jg], bG = biasg[64 + jg], bO = biasg[96 + jg];
            #pragma unroll
            for (int mb = 0; mb < 4; ++mb) {
                float gi = acc[mb][0] + bI, gf = acc[mb][1] + bF;
                float gg = acc[mb][2] + bG, go = acc[mb][3] + bO;
                float c = sigf(gf) * cG2[mb] + sigf(gi) * tanh_(gg);
                cG2[mb] = c;
                h2G[mb] = sigf(go) * tanh_(c);
            }
        }
        __syncthreads();   // B2
        #pragma unroll
        for (int mb = 0; mb < 4; ++mb) {
            int p = mb * 16 + pcol;
            u16 h = bhi(h2G[mb]);
            AGh[p * EAP + 32 + jg] = h;  AGl[p * EAP + 32 + jg] = bhi(h2G[mb] - bf2f(h));
        }
        if (t == OBS - 1) {
            #pragma unroll
            for (int mb = 0; mb < 4; ++mb)
                wsG[(size_t)jg * NTOT + g * 64 + mb * 16 + pcol] = h2G[mb];
        }
    }
}

// ====================== D: decoder (operand-swapped, register dot) ========
__global__ __launch_bounds__(512, 1)
void stgat_dec(const float* __restrict__ obs,
               const float* __restrict__ zin,
               const float* __restrict__ w_ih_p,
               const float* __restrict__ w_hh_p,
               const float* __restrict__ b_ih_p,
               const float* __restrict__ b_hh_p,
               const float* __restrict__ w_out,
               const float* __restrict__ b_out,
               const float* __restrict__ wsT,
               const float* __restrict__ wsG,
               float* __restrict__ out)
{
    const int g    = blockIdx.x;
    const int lane = threadIdx.x & 63;
    const int wv   = __builtin_amdgcn_readfirstlane((int)(threadIdx.x >> 6));
    const int n    = g * NPED + lane;

    __shared__ __attribute__((aligned(16))) u16 Apack[4 * 64 * AP];
    __shared__ __attribute__((aligned(16))) short8_t WloS[18 * 3 * 64];
    __shared__ float red0[512], red1[512];
    u16* AhiA = Apack;
    u16* AloA = AhiA + 64 * AP;
    u16* AhiB = AloA + 64 * AP;
    u16* AloB = AhiB + 64 * AP;

    const int pfrag = lane & 15, kgrp = (lane >> 4) * 8;
    const int pcol  = lane & 15;

    short8_t wfh[3][3];
    {
        const int col = lane & 15, lb = lane >> 4;
        #pragma unroll
        for (int s = 0; s < 3; ++s) {
            if (s < 2 || wv < 2) {
                int nb = wv + 8 * s;
                int gp = nb * 16 + col;
                int j = gp >> 2, ty = gp & 3;
                int orig = ty * HP_ + j;
                #pragma unroll
                for (int kb = 0; kb < 3; ++kb) {
                    short8_t fh, fl;
                    #pragma unroll
                    for (int jj = 0; jj < 8; ++jj) {
                        int k = kb * 32 + lb * 8 + jj;
                        float v;
                        if (k < 72)       v = w_hh_p[orig * HP_ + k];
                        else if (k == 72) v = w_ih_p[orig * 2 + 0];
                        else if (k == 73) v = w_ih_p[orig * 2 + 1];
                        else if (k == 74) v = b_ih_p[orig] + b_hh_p[orig];
                        else              v = 0.0f;
                        u16 hb = bhi(v);
                        fh[jj] = (short)hb;
                        fl[jj] = (short)bhi(v - bf2f(hb));
                    }
                    wfh[s][kb] = fh;
                    WloS[(nb * 3 + kb) * 64 + lane] = fl;
                }
            }
        }
    }
    // per-thread w_out values for owned j's (j = (wv+8s)*4 + (lane>>4))
    float wo0[3] = {0.f, 0.f, 0.f}, wo1[3] = {0.f, 0.f, 0.f};
    #pragma unroll
    for (int s = 0; s < 3; ++s) {
        if (s < 2 || wv < 2) {
            int j = (wv + 8 * s) * 4 + (lane >> 4);
            wo0[s] = w_out[j];
            wo1[s] = w_out[HP_ + j];
        }
    }
    const float bo0 = b_out[0], bo1 = b_out[1];

    {
        float px0 = obs[(7 * NTOT + n) * 3 + 0];
        float px1 = obs[(7 * NTOT + n) * 3 + 1];
        #pragma unroll
        for (int kk = 0; kk < 12; ++kk) {
            int k = wv + kk * 8;
            float va, vb;
            if (k < 32)       { va = wsT[(size_t)k * NTOT + n];            vb = 0.0f; }
            else if (k < 64)  { va = vb = wsG[(size_t)(k - 32) * NTOT + n]; }
            else if (k < 72)  { va = vb = zin[g * NZ_ + (k - 64)]; }
            else if (k == 72) { va = vb = px0; }
            else if (k == 73) { va = vb = px1; }
            else if (k == 74) { va = vb = 1.0f; }
            else              { va = vb = 0.0f; }
            u16 ha = bhi(va); u16 la = bhi(va - bf2f(ha));
            u16 hb = bhi(vb); u16 lb_ = bhi(vb - bf2f(hb));
            AhiA[lane * AP + k] = ha;  AloA[lane * AP + k] = la;
            AhiB[lane * AP + k] = hb;  AloB[lane * AP + k] = lb_;
        }
    }
    __syncthreads();

    float cstA[3][4], cstB[3][4];
    #pragma unroll
    for (int s = 0; s < 3; ++s)
        #pragma unroll
        for (int mb = 0; mb < 4; ++mb) { cstA[s][mb] = 0.0f; cstB[s][mb] = 0.0f; }

    for (int st = 0; st < FUT; ++st) {
        float h2A[3][4], h2B[3][4];
        // ---- cell A: swapped GEMM + direct quad update (no transpose) ----
        {
            f32x4 acc[3][4];
            #pragma unroll
            for (int s = 0; s < 3; ++s)
                #pragma unroll
                for (int mb = 0; mb < 4; ++mb) acc[s][mb] = (f32x4){0.f, 0.f, 0.f, 0.f};
            #pragma unroll
            for (int kb = 0; kb < 3; ++kb) {
                short8_t ah[4], al[4];
                #pragma unroll
                for (int mb = 0; mb < 4; ++mb) {
                    int off = (mb * 16 + pfrag) * AP + kb * 32 + kgrp;
                    ah[mb] = *(const short8_t*)&AhiA[off];
                    al[mb] = *(const short8_t*)&AloA[off];
                }
                #pragma unroll
                for (int s = 0; s < 3; ++s) {
                    if (s < 2 || wv < 2) {
                        int nb = wv + 8 * s;
                        short8_t wl = WloS[(nb * 3 + kb) * 64 + lane];
                        #pragma unroll
                        for (int mb = 0; mb < 4; ++mb) {
                            acc[s][mb] = __builtin_amdgcn_mfma_f32_16x16x32_bf16(wfh[s][kb], ah[mb], acc[s][mb], 0, 0, 0);
                            acc[s][mb] = __builtin_amdgcn_mfma_f32_16x16x32_bf16(wl,         ah[mb], acc[s][mb], 0, 0, 0);
                            acc[s][mb] = __builtin_amdgcn_mfma_f32_16x16x32_bf16(wfh[s][kb], al[mb], acc[s][mb], 0, 0, 0);
                        }
                    }
                }
            }
            #pragma unroll
            for (int s = 0; s < 3; ++s)
                if (s < 2 || wv < 2)
                    #pragma unroll
                    for (int mb = 0; mb < 4; ++mb) {
                        float gi = acc[s][mb][0], gf = acc[s][mb][1];
                        float gg = acc[s][mb][2], go = acc[s][mb][3];
                        float c = sigf(gf) * cstA[s][mb] + sigf(gi) * tanh_(gg);
                        cstA[s][mb] = c;
                        h2A[s][mb] = sigf(go) * tanh_(c);
                    }
        }
        // ---- cell B ----
        {
            f32x4 acc[3][4];
            #pragma unroll
            for (int s = 0; s < 3; ++s)
                #pragma unroll
                for (int mb = 0; mb < 4; ++mb) acc[s][mb] = (f32x4){0.f, 0.f, 0.f, 0.f};
            #pragma unroll
            for (int kb = 0; kb < 3; ++kb) {
                short8_t bh[4], bl[4];
                #pragma unroll
                for (int mb = 0; mb < 4; ++mb) {
                    int off = (mb * 16 + pfrag) * AP + kb * 32 + kgrp;
                    bh[mb] = *(const short8_t*)&AhiB[off];
                    bl[mb] = *(const short8_t*)&AloB[off];
                }
                #pragma unroll
                for (int s = 0; s < 3; ++s) {
                    if (s < 2 || wv < 2) {
                        int nb = wv + 8 * s;
                        short8_t wl = WloS[(nb * 3 + kb) * 64 + lane];
                        #pragma unroll
                        for (int mb = 0; mb < 4; ++mb) {
                            acc[s][mb] = __builtin_amdgcn_mfma_f32_16x16x32_bf16(wfh[s][kb], bh[mb], acc[s][mb], 0, 0, 0);
                            acc[s][mb] = __builtin_amdgcn_mfma_f32_16x16x32_bf16(wl,         bh[mb], acc[s][mb], 0, 0, 0);
                            acc[s][mb] = __builtin_amdgcn_mfma_f32_16x16x32_bf16(wfh[s][kb], bl[mb], acc[s][mb], 0, 0, 0);
                        }
                    }
                }
            }
            #pragma unroll
            for (int s = 0; s < 3; ++s)
                if (s < 2 || wv < 2)
                    #pragma unroll
                    for (int mb = 0; mb < 4; ++mb) {
                        float gi = acc[s][mb][0], gf = acc[s][mb][1];
                        float gg = acc[s][mb][2], go = acc[s][mb][3];
                        float c = sigf(gf) * cstB[s][mb] + sigf(gi) * tanh_(gg);
                        cstB[s][mb] = c;
                        h2B[s][mb] = sigf(go) * tanh_(c);
                    }
        }
        // ---- register partial dot + j-reduction via shfl ----
        float po0[4] = {0.f, 0.f, 0.f, 0.f}, po1[4] = {0.f, 0.f, 0.f, 0.f};
        #pragma unroll
        for (int s = 0; s < 3; ++s)
            if (s < 2 || wv < 2)
                #pragma unroll
                for (int mb = 0; mb < 4; ++mb) {
                    float dh = h2A[s][mb] - h2B[s][mb];
                    po0[mb] += wo0[s] * dh;
                    po1[mb] += wo1[s] * dh;
                }
        #pragma unroll
        for (int mb = 0; mb < 4; ++mb) {
            po0[mb] += __shfl_xor(po0[mb], 16);  po0[mb] += __shfl_xor(po0[mb], 32);
            po1[mb] += __shfl_xor(po1[mb], 16);  po1[mb] += __shfl_xor(po1[mb], 32);
        }
        __syncthreads();   // B1: all GEMM reads of Apack done
        // ---- h2 write-back (thread owns ped = mb*16+pcol, j fixed per s) ----
        #pragma unroll
        for (int s = 0; s < 3; ++s) {
            if (s < 2 || wv < 2) {
                int j = (wv + 8 * s) * 4 + (lane >> 4);
                #pragma unroll
                for (int mb = 0; mb < 4; ++mb) {
                    int p = mb * 16 + pcol;
                    u16 ha = bhi(h2A[s][mb]);
                    AhiA[p * AP + j] = ha;  AloA[p * AP + j] = bhi(h2A[s][mb] - bf2f(ha));
                    u16 hb = bhi(h2B[s][mb]);
                    AhiB[p * AP + j] = hb;  AloB[p * AP + j] = bhi(h2B[s][mb] - bf2f(hb));
                }
            }
        }
        if ((lane >> 4) == 0) {
            #pragma unroll
            for (int mb = 0; mb < 4; ++mb) {
                red0[wv * 64 + mb * 16 + lane] = po0[mb];
                red1[wv * 64 + mb * 16 + lane] = po1[mb];
            }
        }
        __syncthreads();   // B2: h2 + partials visible
        if (wv == 0) {     // lane == ped
            float o0 = bo0, o1 = bo1;
            #pragma unroll
            for (int w = 0; w < 8; ++w) { o0 += red0[w * 64 + lane]; o1 += red1[w * 64 + lane]; }
            *reinterpret_cast<float2*>(&out[(size_t)(st * NTOT + n) * 2]) = make_float2(o0, o1);
            u16 h0_ = bhi(o0); u16 l0 = bhi(o0 - bf2f(h0_));
            u16 h1 = bhi(o1); u16 l1 = bhi(o1 - bf2f(h1));
            AhiA[lane * AP + 72] = h0_;  AloA[lane * AP + 72] = l0;
            AhiB[lane * AP + 72] = h0_;  AloB[lane * AP + 72] = l0;
            AhiA[lane * AP + 73] = h1;   AloA[lane * AP + 73] = l1;
            AhiB[lane * AP + 73] = h1;   AloB[lane * AP + 73] = l1;
        }
        __syncthreads();   // B3: px visible for next step
    }
}

extern "C" void kernel_launch(void* const* d_in, const int* in_sizes, int n_in,
                              void* d_out, int out_size, void* d_ws, size_t ws_size,
                              hipStream_t stream) {
    (void)in_sizes; (void)n_in; (void)out_size; (void)ws_size;
    const size_t NF = (size_t)OBS * 32 * NTOT;
    float* ws1 = (float*)d_ws;
    float* ws2 = ws1 + NF;
    float* wsT = ws2 + NF;
    float* wsG = wsT + (size_t)32 * NTOT;

    traj_lstm_k<<<dim3(NTOT / 256), dim3(256), 0, stream>>>(
        (const float*)d_in[0], (const float*)d_in[2], (const float*)d_in[3],
        (const float*)d_in[6], (const float*)d_in[7], (const float*)d_in[8], (const float*)d_in[9],
        ws1, wsT);

    gat_k<<<dim3(OBS * NGR), dim3(512), 0, stream>>>(
        ws1,
        (const float*)d_in[10], (const float*)d_in[11], (const float*)d_in[12], (const float*)d_in[13],
        (const float*)d_in[14], (const float*)d_in[15], (const float*)d_in[16], (const float*)d_in[17],
        ws2);

    graph_lstm_k<<<dim3(NGR), dim3(512), 0, stream>>>(
        ws2, (const float*)d_in[4], (const float*)d_in[5],
        (const float*)d_in[18], (const float*)d_in[19], (const float*)d_in[20], (const float*)d_in[21],
        wsG);

    stgat_dec<<<dim3(NGR), dim3(512), 0, stream>>>(
        (const float*)d_in[0], (const float*)d_in[1],
        (const float*)d_in[22], (const float*)d_in[23],
        (const float*)d_in[24], (const float*)d_in[25],
        (const float*)d_in[26], (const float*)d_in[27],
        wsT, wsG, (float*)d_out);
}

// Round 11
// 1233.201 us; speedup vs baseline: 1.2290x; 1.0374x over previous
//
#include <hip/hip_runtime.h>

// STGAT round 11: fix round 10's NaN — the kb=2 MFMA fragment read spans
// k in [64,96) but AP2=80 rows overrun into the next row; the LAST row of
// AhiB overran into unallocated LDS (stale bits -> bf16 NaN; 0*NaN=NaN).
// Fix: single fused A-array + 16-u16 zeroed guard tail. LDS 79.9KB (2 blk/CU).
// All else identical to round 10; traj/gat/graph = round 9 verbatim.

#define OBS 8
#define FUT 12
#define NPED 64
#define HT_ 32
#define HG_ 32
#define NZ_ 8
#define HP_ 72
#define NGR 1024
#define NTOT (NGR * NPED)
#define AP2 80
#define EAP 72

typedef __attribute__((ext_vector_type(8))) short short8_t;
typedef __attribute__((ext_vector_type(4))) float f32x4;
typedef unsigned short u16;

__device__ __forceinline__ float sigf(float x) { return 1.0f / (1.0f + __expf(-x)); }
__device__ __forceinline__ float tanh_(float x) {
    float e = __expf(2.0f * x);
    return 1.0f - 2.0f / (e + 1.0f);
}
__device__ __forceinline__ float leaky(float x) { return (x > 0.0f) ? x : 0.2f * x; }
__device__ __forceinline__ u16 bhi(float v) {
    unsigned u = __float_as_uint(v);
    return (u16)((u + 0x7FFFu + ((u >> 16) & 1u)) >> 16);
}
__device__ __forceinline__ float bf2f(u16 h) { return __uint_as_float(((unsigned)h) << 16); }

// ====================== A: traj LSTM (no barriers) ========================
__global__ __launch_bounds__(256, 1)
void traj_lstm_k(const float* __restrict__ obs,
                 const float* __restrict__ h0,
                 const float* __restrict__ c0,
                 const float* __restrict__ w_ih,
                 const float* __restrict__ w_hh,
                 const float* __restrict__ b_ih,
                 const float* __restrict__ b_hh,
                 float* __restrict__ ws1,    // xn f32 [8][32][N]
                 float* __restrict__ wsT)    // raw h at t=7, [32][N]
{
    const int tid = threadIdx.x;
    const int n   = blockIdx.x * 256 + tid;
    __shared__ __attribute__((aligned(16))) float W[128 * 36];
    __shared__ float hc[256 * 33 * 2];
    float* hl = &hc[tid * 33];
    float* cl = &hc[(256 + tid) * 33];

    for (int i = tid; i < 128 * 36; i += 256) {
        int gate = i / 36, k = i - gate * 36;
        float v;
        if (k < 32)      v = w_hh[gate * 32 + k];
        else if (k < 35) v = w_ih[gate * 3 + (k - 32)];
        else             v = b_ih[gate] + b_hh[gate];
        W[i] = v;
    }
    #pragma unroll
    for (int j4 = 0; j4 < 8; ++j4) {
        f32x4 hv = *(const f32x4*)&h0[(size_t)n * 32 + j4 * 4];
        f32x4 cv = *(const f32x4*)&c0[(size_t)n * 32 + j4 * 4];
        #pragma unroll
        for (int r = 0; r < 4; ++r) { hl[j4 * 4 + r] = hv[r]; cl[j4 * 4 + r] = cv[r]; }
    }
    __syncthreads();

    for (int t = 0; t < OBS; ++t) {
        f32x4 v4[9];
        #pragma unroll
        for (int kq = 0; kq < 8; ++kq) {
            f32x4 x;
            #pragma unroll
            for (int r = 0; r < 4; ++r) x[r] = hl[kq * 4 + r];
            v4[kq] = x;
        }
        {
            const float* ob = &obs[((size_t)t * NTOT + n) * 3];
            v4[8] = (f32x4){ob[0], ob[1], ob[2], 1.0f};
        }
        #pragma unroll 4
        for (int j = 0; j < 32; ++j) {
            f32x4 ai = {0,0,0,0}, af4 = {0,0,0,0}, ag4 = {0,0,0,0}, ao4 = {0,0,0,0};
            #pragma unroll
            for (int kq = 0; kq < 9; ++kq) {
                ai  += *(const f32x4*)&W[(j)      * 36 + kq * 4] * v4[kq];
                af4 += *(const f32x4*)&W[(32 + j) * 36 + kq * 4] * v4[kq];
                ag4 += *(const f32x4*)&W[(64 + j) * 36 + kq * 4] * v4[kq];
                ao4 += *(const f32x4*)&W[(96 + j) * 36 + kq * 4] * v4[kq];
            }
            float gi = (ai[0]  + ai[1])  + (ai[2]  + ai[3]);
            float gf = (af4[0] + af4[1]) + (af4[2] + af4[3]);
            float gg = (ag4[0] + ag4[1]) + (ag4[2] + ag4[3]);
            float go = (ao4[0] + ao4[1]) + (ao4[2] + ao4[3]);
            float cc = sigf(gf) * cl[j] + sigf(gi) * tanh_(gg);
            cl[j] = cc;
            hl[j] = sigf(go) * tanh_(cc);
        }
        #pragma unroll 4
        for (int f = 0; f < 32; ++f) {
            float v = hl[f];
            float sm = v, sq = v * v;
            #pragma unroll
            for (int m = 1; m < 64; m <<= 1) { sm += __shfl_xor(sm, m); sq += __shfl_xor(sq, m); }
            float mean = sm * (1.0f / 64.0f);
            float var  = sq * (1.0f / 64.0f) - mean * mean;
            ws1[((size_t)t * 32 + f) * NTOT + n] = (v - mean) * rsqrtf(var + 1e-5f);
        }
        if (t == OBS - 1) {
            #pragma unroll 4
            for (int f = 0; f < 32; ++f) wsT[(size_t)f * NTOT + n] = hl[f];
        }
    }
}

// ====================== B: GAT, one block per (t,g) =======================
__global__ __launch_bounds__(512, 2)
void gat_k(const float* __restrict__ ws1,
           const float* __restrict__ g1w,
           const float* __restrict__ g1as,
           const float* __restrict__ g1ad,
           const float* __restrict__ g1b,
           const float* __restrict__ g2w,
           const float* __restrict__ g2as,
           const float* __restrict__ g2ad,
           const float* __restrict__ g2b,
           float* __restrict__ ws2)
{
    const int t    = blockIdx.x >> 10;
    const int g    = blockIdx.x & 1023;
    const int lane = threadIdx.x & 63;
    const int wv   = __builtin_amdgcn_readfirstlane((int)(threadIdx.x >> 6));

    __shared__ float hp1s[4096];
    __shared__ float xnx[4096];
    __shared__ float sp1s[512], dp1s[512], sp2s[512], dp2s[512];
    float* xn  = xnx;
    float* x2  = xnx;
    float* hp2 = hp1s;

    #pragma unroll
    for (int r = 0; r < 4; ++r) {
        int f = wv * 4 + r;
        xn[f * 64 + lane] = ws1[((size_t)t * 32 + f) * NTOT + g * 64 + lane];
    }
    __syncthreads();
    {
        const int h_ = wv >> 1;
        const int o0 = (wv & 1) * 8;
        float acc[8];
        #pragma unroll
        for (int q = 0; q < 8; ++q) acc[q] = 0.0f;
        for (int k8 = 0; k8 < 4; ++k8) {
            float xk[8];
            #pragma unroll
            for (int i = 0; i < 8; ++i) xk[i] = xn[(k8 * 8 + i) * 64 + lane];
            #pragma unroll
            for (int i = 0; i < 8; ++i)
                #pragma unroll
                for (int q = 0; q < 8; ++q)
                    acc[q] += g1w[h_ * 512 + (k8 * 8 + i) * 16 + o0 + q] * xk[i];
        }
        float ps = 0.0f, pd = 0.0f;
        #pragma unroll
        for (int q = 0; q < 8; ++q) {
            hp1s[(h_ * 16 + o0 + q) * 64 + lane] = acc[q];
            ps += acc[q] * g1as[h_ * 16 + o0 + q];
            pd += acc[q] * g1ad[h_ * 16 + o0 + q];
        }
        sp1s[((wv & 1) * 4 + h_) * 64 + lane] = ps;
        dp1s[((wv & 1) * 4 + h_) * 64 + lane] = pd;
    }
    __syncthreads();
    {
        const int h_ = wv >> 1;
        const int o0 = (wv & 1) * 8;
        const float sv   = sp1s[h_ * 64 + lane] + sp1s[(4 + h_) * 64 + lane];
        const float dtot = dp1s[h_ * 64 + lane] + dp1s[(4 + h_) * 64 + lane];
        float sum = 0.0f;
        float acc[8];
        #pragma unroll
        for (int q = 0; q < 8; ++q) acc[q] = 0.0f;
        #pragma unroll
        for (int m4 = 0; m4 < 16; ++m4) {
            float e0 = __expf(leaky(sv + __shfl(dtot, m4 * 4 + 0)));
            float e1 = __expf(leaky(sv + __shfl(dtot, m4 * 4 + 1)));
            float e2 = __expf(leaky(sv + __shfl(dtot, m4 * 4 + 2)));
            float e3 = __expf(leaky(sv + __shfl(dtot, m4 * 4 + 3)));
            sum += e0 + e1 + e2 + e3;
            #pragma unroll
            for (int q = 0; q < 8; ++q) {
                float4 hv = *reinterpret_cast<const float4*>(&hp1s[(h_ * 16 + o0 + q) * 64 + m4 * 4]);
                acc[q] += e0 * hv.x + e1 * hv.y + e2 * hv.z + e3 * hv.w;
            }
        }
        float rs = 1.0f / sum;
        #pragma unroll
        for (int q = 0; q < 8; ++q) {
            float v = acc[q] * rs + g1b[o0 + q];
            v = (v > 0.0f) ? v : (__expf(v) - 1.0f);
            float sm = v, sq = v * v;
            #pragma unroll
            for (int m = 1; m < 64; m <<= 1) { sm += __shfl_xor(sm, m); sq += __shfl_xor(sq, m); }
            float mean = sm * (1.0f / 64.0f);
            float var  = sq * (1.0f / 64.0f) - mean * mean;
            x2[(h_ * 16 + o0 + q) * 64 + lane] = (v - mean) * rsqrtf(var + 1e-5f);
        }
    }
    __syncthreads();
    {
        float acc[4];
        #pragma unroll
        for (int q = 0; q < 4; ++q) acc[q] = 0.0f;
        for (int k8 = 0; k8 < 8; ++k8) {
            float xk[8];
            #pragma unroll
            for (int i = 0; i < 8; ++i) xk[i] = x2[(k8 * 8 + i) * 64 + lane];
            #pragma unroll
            for (int i = 0; i < 8; ++i)
                #pragma unroll
                for (int q = 0; q < 4; ++q)
                    acc[q] += g2w[(k8 * 8 + i) * 32 + wv * 4 + q] * xk[i];
        }
        float ps = 0.0f, pd = 0.0f;
        #pragma unroll
        for (int q = 0; q < 4; ++q) {
            hp2[(wv * 4 + q) * 64 + lane] = acc[q];
            ps += acc[q] * g2as[wv * 4 + q];
            pd += acc[q] * g2ad[wv * 4 + q];
        }
        sp2s[wv * 64 + lane] = ps;
        dp2s[wv * 64 + lane] = pd;
    }
    __syncthreads();
    {
        float sv = 0.0f, dtot = 0.0f;
        #pragma unroll
        for (int w = 0; w < 8; ++w) { sv += sp2s[w * 64 + lane]; dtot += dp2s[w * 64 + lane]; }
        float sum = 0.0f;
        float acc[4];
        #pragma unroll
        for (int q = 0; q < 4; ++q) acc[q] = 0.0f;
        #pragma unroll
        for (int m4 = 0; m4 < 16; ++m4) {
            float e0 = __expf(leaky(sv + __shfl(dtot, m4 * 4 + 0)));
            float e1 = __expf(leaky(sv + __shfl(dtot, m4 * 4 + 1)));
            float e2 = __expf(leaky(sv + __shfl(dtot, m4 * 4 + 2)));
            float e3 = __expf(leaky(sv + __shfl(dtot, m4 * 4 + 3)));
            sum += e0 + e1 + e2 + e3;
            #pragma unroll
            for (int q = 0; q < 4; ++q) {
                float4 hv = *reinterpret_cast<const float4*>(&hp2[(wv * 4 + q) * 64 + m4 * 4]);
                acc[q] += e0 * hv.x + e1 * hv.y + e2 * hv.z + e3 * hv.w;
            }
        }
        float rs = 1.0f / sum;
        #pragma unroll
        for (int q = 0; q < 4; ++q)
            ws2[((size_t)t * 32 + wv * 4 + q) * NTOT + g * 64 + lane] = acc[q] * rs + g2b[wv * 4 + q];
    }
}

// ====================== C: graph LSTM (MFMA, operand-swapped) =============
__global__ __launch_bounds__(512, 1)
void graph_lstm_k(const float* __restrict__ ws2,
                  const float* __restrict__ graph_h0,
                  const float* __restrict__ graph_c0,
                  const float* __restrict__ w_ih_g,
                  const float* __restrict__ w_hh_g,
                  const float* __restrict__ b_ih_g,
                  const float* __restrict__ b_hh_g,
                  float* __restrict__ wsG)
{
    const int g    = blockIdx.x;
    const int lane = threadIdx.x & 63;
    const int wv   = __builtin_amdgcn_readfirstlane((int)(threadIdx.x >> 6));
    const int n    = g * NPED + lane;

    __shared__ __attribute__((aligned(16))) u16 AGh[64 * EAP], AGl[64 * EAP];
    __shared__ float biasg[128];

    const int pfrag = lane & 15, kg8 = (lane >> 4) * 8;
    const int pcol = lane & 15;
    const int jg   = wv * 4 + (lane >> 4);

    short8_t wfhG[2], wflG[2];
    {
        int gp = wv * 16 + pfrag, j = gp >> 2, ty = gp & 3, orig = ty * 32 + j;
        #pragma unroll
        for (int kb = 0; kb < 2; ++kb) {
            short8_t fhG, flG;
            #pragma unroll
            for (int jj = 0; jj < 8; ++jj) {
                int k = kb * 32 + (lane >> 4) * 8 + jj;
                float vG = (k < 32) ? w_ih_g[orig * 32 + k] : w_hh_g[orig * 32 + (k - 32)];
                u16 hG = bhi(vG); fhG[jj] = (short)hG; flG[jj] = (short)bhi(vG - bf2f(hG));
            }
            wfhG[kb] = fhG; wflG[kb] = flG;
        }
    }
    #pragma unroll
    for (int r = 0; r < 4; ++r) {
        int j = wv * 4 + r;
        float vg = graph_h0[(size_t)n * HG_ + j];
        u16 hg = bhi(vg);
        AGh[lane * EAP + 32 + j] = hg;  AGl[lane * EAP + 32 + j] = bhi(vg - bf2f(hg));
    }
    float cG2[4];
    #pragma unroll
    for (int mb = 0; mb < 4; ++mb)
        cG2[mb] = graph_c0[(size_t)(g * 64 + mb * 16 + pcol) * HG_ + jg];
    if (threadIdx.x < 128) biasg[threadIdx.x] = b_ih_g[threadIdx.x] + b_hh_g[threadIdx.x];

    for (int t = 0; t < OBS; ++t) {
        #pragma unroll
        for (int r = 0; r < 4; ++r) {
            int f = wv * 4 + r;
            float v = ws2[((size_t)t * 32 + f) * NTOT + g * 64 + lane];
            u16 h = bhi(v);
            AGh[lane * EAP + f] = h;  AGl[lane * EAP + f] = bhi(v - bf2f(h));
        }
        __syncthreads();   // B1
        float h2G[4];
        {
            f32x4 acc[4];
            #pragma unroll
            for (int mb = 0; mb < 4; ++mb) acc[mb] = (f32x4){0.f, 0.f, 0.f, 0.f};
            #pragma unroll
            for (int kb = 0; kb < 2; ++kb) {
                short8_t ah[4], al[4];
                #pragma unroll
                for (int mb = 0; mb < 4; ++mb) {
                    int off = (mb * 16 + pfrag) * EAP + kb * 32 + kg8;
                    ah[mb] = *(const short8_t*)&AGh[off];
                    al[mb] = *(const short8_t*)&AGl[off];
                }
                #pragma unroll
                for (int mb = 0; mb < 4; ++mb) {
                    acc[mb] = __builtin_amdgcn_mfma_f32_16x16x32_bf16(wfhG[kb], ah[mb], acc[mb], 0, 0, 0);
                    acc[mb] = __builtin_amdgcn_mfma_f32_16x16x32_bf16(wflG[kb], ah[mb], acc[mb], 0, 0, 0);
                    acc[mb] = __builtin_amdgcn_mfma_f32_16x16x32_bf16(wfhG[kb], al[mb], acc[mb], 0, 0, 0);
                }
            }
            const float bI = biasg[jg], bF = biasg[32 + jg], bG = biasg[64 + jg], bO = biasg[96 + jg];
            #pragma unroll
            for (int mb = 0; mb < 4; ++mb) {
                float gi = acc[mb][0] + bI, gf = acc[mb][1] + bF;
                float gg = acc[mb][2] + bG, go = acc[mb][3] + bO;
                float c = sigf(gf) * cG2[mb] + sigf(gi) * tanh_(gg);
                cG2[mb] = c;
                h2G[mb] = sigf(go) * tanh_(c);
            }
        }
        __syncthreads();   // B2
        #pragma unroll
        for (int mb = 0; mb < 4; ++mb) {
            int p = mb * 16 + pcol;
            u16 h = bhi(h2G[mb]);
            AGh[p * EAP + 32 + jg] = h;  AGl[p * EAP + 32 + jg] = bhi(h2G[mb] - bf2f(h));
        }
        if (t == OBS - 1) {
            #pragma unroll
            for (int mb = 0; mb < 4; ++mb)
                wsG[(size_t)jg * NTOT + g * 64 + mb * 16 + pcol] = h2G[mb];
        }
    }
}

// ====================== D: decoder (hi-only A + guard, 80KB LDS) ==========
__global__ __launch_bounds__(512, 1)
void stgat_dec(const float* __restrict__ obs,
               const float* __restrict__ zin,
               const float* __restrict__ w_ih_p,
               const float* __restrict__ w_hh_p,
               const float* __restrict__ b_ih_p,
               const float* __restrict__ b_hh_p,
               const float* __restrict__ w_out,
               const float* __restrict__ b_out,
               const float* __restrict__ wsT,
               const float* __restrict__ wsG,
               float* __restrict__ out)
{
    const int g    = blockIdx.x;
    const int lane = threadIdx.x & 63;
    const int wv   = __builtin_amdgcn_readfirstlane((int)(threadIdx.x >> 6));
    const int n    = g * NPED + lane;

    // Fused A-pack: AhiA rows | AhiB rows | 16-u16 guard (zeroed).
    // kb=2 fragment reads span k in [64,96): rows overrun 16 u16 into the
    // following row; the guard makes the final overrun read finite zeros.
    __shared__ __attribute__((aligned(16))) u16 Apk[2 * 64 * AP2 + 16]; // 20512 B
    __shared__ __attribute__((aligned(16))) short8_t WloS[18 * 3 * 64]; // 55296 B
    __shared__ float red0[512], red1[512];                              // 4096 B
    u16* AhiA = Apk;
    u16* AhiB = Apk + 64 * AP2;

    const int pfrag = lane & 15, kgrp = (lane >> 4) * 8;
    const int pcol  = lane & 15;

    short8_t wfh[3][3];
    {
        const int col = lane & 15, lb = lane >> 4;
        #pragma unroll
        for (int s = 0; s < 3; ++s) {
            if (s < 2 || wv < 2) {
                int nb = wv + 8 * s;
                int gp = nb * 16 + col;
                int j = gp >> 2, ty = gp & 3;
                int orig = ty * HP_ + j;
                #pragma unroll
                for (int kb = 0; kb < 3; ++kb) {
                    short8_t fh, fl;
                    #pragma unroll
                    for (int jj = 0; jj < 8; ++jj) {
                        int k = kb * 32 + lb * 8 + jj;
                        float v;
                        if (k < 72)       v = w_hh_p[orig * HP_ + k];
                        else if (k == 72) v = w_ih_p[orig * 2 + 0];
                        else if (k == 73) v = w_ih_p[orig * 2 + 1];
                        else if (k == 74) v = b_ih_p[orig] + b_hh_p[orig];
                        else              v = 0.0f;
                        u16 hb = bhi(v);
                        fh[jj] = (short)hb;
                        fl[jj] = (short)bhi(v - bf2f(hb));
                    }
                    wfh[s][kb] = fh;
                    WloS[(nb * 3 + kb) * 64 + lane] = fl;
                }
            }
        }
    }
    float wo0[3] = {0.f, 0.f, 0.f}, wo1[3] = {0.f, 0.f, 0.f};
    #pragma unroll
    for (int s = 0; s < 3; ++s) {
        if (s < 2 || wv < 2) {
            int j = (wv + 8 * s) * 4 + (lane >> 4);
            wo0[s] = w_out[j];
            wo1[s] = w_out[HP_ + j];
        }
    }
    const float bo0 = b_out[0], bo1 = b_out[1];

    {
        float px0 = obs[(7 * NTOT + n) * 3 + 0];
        float px1 = obs[(7 * NTOT + n) * 3 + 1];
        #pragma unroll
        for (int kk = 0; kk < 12; ++kk) {
            int k = wv + kk * 8;
            if (k < AP2) {
                float va, vb;
                if (k < 32)       { va = wsT[(size_t)k * NTOT + n];            vb = 0.0f; }
                else if (k < 64)  { va = vb = wsG[(size_t)(k - 32) * NTOT + n]; }
                else if (k < 72)  { va = vb = zin[g * NZ_ + (k - 64)]; }
                else if (k == 72) { va = vb = px0; }
                else if (k == 73) { va = vb = px1; }
                else if (k == 74) { va = vb = 1.0f; }
                else              { va = vb = 0.0f; }
                AhiA[lane * AP2 + k] = bhi(va);
                AhiB[lane * AP2 + k] = bhi(vb);
            }
        }
        if (wv == 0 && lane < 16) Apk[2 * 64 * AP2 + lane] = 0;   // guard
    }
    __syncthreads();

    float cstA[3][4], cstB[3][4];
    #pragma unroll
    for (int s = 0; s < 3; ++s)
        #pragma unroll
        for (int mb = 0; mb < 4; ++mb) { cstA[s][mb] = 0.0f; cstB[s][mb] = 0.0f; }

    for (int st = 0; st < FUT; ++st) {
        float h2A[3][4], h2B[3][4];
        // ---- cell A: swapped GEMM (2 products) + direct quad update ----
        {
            f32x4 acc[3][4];
            #pragma unroll
            for (int s = 0; s < 3; ++s)
                #pragma unroll
                for (int mb = 0; mb < 4; ++mb) acc[s][mb] = (f32x4){0.f, 0.f, 0.f, 0.f};
            #pragma unroll
            for (int kb = 0; kb < 3; ++kb) {
                short8_t ah[4];
                #pragma unroll
                for (int mb = 0; mb < 4; ++mb) {
                    int off = (mb * 16 + pfrag) * AP2 + kb * 32 + kgrp;
                    ah[mb] = *(const short8_t*)&AhiA[off];
                }
                #pragma unroll
                for (int s = 0; s < 3; ++s) {
                    if (s < 2 || wv < 2) {
                        int nb = wv + 8 * s;
                        short8_t wl = WloS[(nb * 3 + kb) * 64 + lane];
                        #pragma unroll
                        for (int mb = 0; mb < 4; ++mb) {
                            acc[s][mb] = __builtin_amdgcn_mfma_f32_16x16x32_bf16(wfh[s][kb], ah[mb], acc[s][mb], 0, 0, 0);
                            acc[s][mb] = __builtin_amdgcn_mfma_f32_16x16x32_bf16(wl,         ah[mb], acc[s][mb], 0, 0, 0);
                        }
                    }
                }
            }
            #pragma unroll
            for (int s = 0; s < 3; ++s)
                if (s < 2 || wv < 2)
                    #pragma unroll
                    for (int mb = 0; mb < 4; ++mb) {
                        float gi = acc[s][mb][0], gf = acc[s][mb][1];
                        float gg = acc[s][mb][2], go = acc[s][mb][3];
                        float c = sigf(gf) * cstA[s][mb] + sigf(gi) * tanh_(gg);
                        cstA[s][mb] = c;
                        h2A[s][mb] = sigf(go) * tanh_(c);
                    }
        }
        // ---- cell B ----
        {
            f32x4 acc[3][4];
            #pragma unroll
            for (int s = 0; s < 3; ++s)
                #pragma unroll
                for (int mb = 0; mb < 4; ++mb) acc[s][mb] = (f32x4){0.f, 0.f, 0.f, 0.f};
            #pragma unroll
            for (int kb = 0; kb < 3; ++kb) {
                short8_t bh[4];
                #pragma unroll
                for (int mb = 0; mb < 4; ++mb) {
                    int off = (mb * 16 + pfrag) * AP2 + kb * 32 + kgrp;
                    bh[mb] = *(const short8_t*)&AhiB[off];
                }
                #pragma unroll
                for (int s = 0; s < 3; ++s) {
                    if (s < 2 || wv < 2) {
                        int nb = wv + 8 * s;
                        short8_t wl = WloS[(nb * 3 + kb) * 64 + lane];
                        #pragma unroll
                        for (int mb = 0; mb < 4; ++mb) {
                            acc[s][mb] = __builtin_amdgcn_mfma_f32_16x16x32_bf16(wfh[s][kb], bh[mb], acc[s][mb], 0, 0, 0);
                            acc[s][mb] = __builtin_amdgcn_mfma_f32_16x16x32_bf16(wl,         bh[mb], acc[s][mb], 0, 0, 0);
                        }
                    }
                }
            }
            #pragma unroll
            for (int s = 0; s < 3; ++s)
                if (s < 2 || wv < 2)
                    #pragma unroll
                    for (int mb = 0; mb < 4; ++mb) {
                        float gi = acc[s][mb][0], gf = acc[s][mb][1];
                        float gg = acc[s][mb][2], go = acc[s][mb][3];
                        float c = sigf(gf) * cstB[s][mb] + sigf(gi) * tanh_(gg);
                        cstB[s][mb] = c;
                        h2B[s][mb] = sigf(go) * tanh_(c);
                    }
        }
        // ---- register partial dot + j-reduction via shfl (f32-exact) ----
        float po0[4] = {0.f, 0.f, 0.f, 0.f}, po1[4] = {0.f, 0.f, 0.f, 0.f};
        #pragma unroll
        for (int s = 0; s < 3; ++s)
            if (s < 2 || wv < 2)
                #pragma unroll
                for (int mb = 0; mb < 4; ++mb) {
                    float dh = h2A[s][mb] - h2B[s][mb];
                    po0[mb] += wo0[s] * dh;
                    po1[mb] += wo1[s] * dh;
                }
        #pragma unroll
        for (int mb = 0; mb < 4; ++mb) {
            po0[mb] += __shfl_xor(po0[mb], 16);  po0[mb] += __shfl_xor(po0[mb], 32);
            po1[mb] += __shfl_xor(po1[mb], 16);  po1[mb] += __shfl_xor(po1[mb], 32);
        }
        __syncthreads();   // B1: all GEMM reads of Apack done
        // ---- h2 write-back (hi only) ----
        #pragma unroll
        for (int s = 0; s < 3; ++s) {
            if (s < 2 || wv < 2) {
                int j = (wv + 8 * s) * 4 + (lane >> 4);
                #pragma unroll
                for (int mb = 0; mb < 4; ++mb) {
                    int p = mb * 16 + pcol;
                    AhiA[p * AP2 + j] = bhi(h2A[s][mb]);
                    AhiB[p * AP2 + j] = bhi(h2B[s][mb]);
                }
            }
        }
        if ((lane >> 4) == 0) {
            #pragma unroll
            for (int mb = 0; mb < 4; ++mb) {
                red0[wv * 64 + mb * 16 + lane] = po0[mb];
                red1[wv * 64 + mb * 16 + lane] = po1[mb];
            }
        }
        __syncthreads();   // B2: h2 + partials visible
        if (wv == 0) {     // lane == ped
            float o0 = bo0, o1 = bo1;
            #pragma unroll
            for (int w = 0; w < 8; ++w) { o0 += red0[w * 64 + lane]; o1 += red1[w * 64 + lane]; }
            *reinterpret_cast<float2*>(&out[(size_t)(st * NTOT + n) * 2]) = make_float2(o0, o1);
            u16 h0_ = bhi(o0);
            u16 h1  = bhi(o1);
            AhiA[lane * AP2 + 72] = h0_;  AhiB[lane * AP2 + 72] = h0_;
            AhiA[lane * AP2 + 73] = h1;   AhiB[lane * AP2 + 73] = h1;
        }
        __syncthreads();   // B3: px visible for next step
    }
}

extern "C" void kernel_launch(void* const* d_in, const int* in_sizes, int n_in,
                              void* d_out, int out_size, void* d_ws, size_t ws_size,
                              hipStream_t stream) {
    (void)in_sizes; (void)n_in; (void)out_size; (void)ws_size;
    const size_t NF = (size_t)OBS * 32 * NTOT;
    float* ws1 = (float*)d_ws;
    float* ws2 = ws1 + NF;
    float* wsT = ws2 + NF;
    float* wsG = wsT + (size_t)32 * NTOT;

    traj_lstm_k<<<dim3(NTOT / 256), dim3(256), 0, stream>>>(
        (const float*)d_in[0], (const float*)d_in[2], (const float*)d_in[3],
        (const float*)d_in[6], (const float*)d_in[7], (const float*)d_in[8], (const float*)d_in[9],
        ws1, wsT);

    gat_k<<<dim3(OBS * NGR), dim3(512), 0, stream>>>(
        ws1,
        (const float*)d_in[10], (const float*)d_in[11], (const float*)d_in[12], (const float*)d_in[13],
        (const float*)d_in[14], (const float*)d_in[15], (const float*)d_in[16], (const float*)d_in[17],
        ws2);

    graph_lstm_k<<<dim3(NGR), dim3(512), 0, stream>>>(
        ws2, (const float*)d_in[4], (const float*)d_in[5],
        (const float*)d_in[18], (const float*)d_in[19], (const float*)d_in[20], (const float*)d_in[21],
        wsG);

    stgat_dec<<<dim3(NGR), dim3(512), 0, stream>>>(
        (const float*)d_in[0], (const float*)d_in[1],
        (const float*)d_in[22], (const float*)d_in[23],
        (const float*)d_in[24], (const float*)d_in[25],
        (const float*)d_in[26], (const float*)d_in[27],
        wsT, wsG, (float*)d_out);
}

// Round 12
// 1199.772 us; speedup vs baseline: 1.2633x; 1.0279x over previous
//
#include <hip/hip_runtime.h>

// STGAT round 12: decoder load-balance. 18 gate-tiles over 8 waves was 3/3/2/2/2/2/2/2
// (barrier syncs to 3-tile waves). Now: every wave = 2 full tiles + 1 quarter-job
// (tile 16+(wv>>2), mb=wv&3) = balanced 2.25 -> critical path -25% MFMA/updates.
// s=2 fragment re-read from LDS (runtime-uniform addr; avoids reg-array dyn index).
// All else identical to round 11.

#define OBS 8
#define FUT 12
#define NPED 64
#define HT_ 32
#define HG_ 32
#define NZ_ 8
#define HP_ 72
#define NGR 1024
#define NTOT (NGR * NPED)
#define AP2 80
#define EAP 72

typedef __attribute__((ext_vector_type(8))) short short8_t;
typedef __attribute__((ext_vector_type(4))) float f32x4;
typedef unsigned short u16;

__device__ __forceinline__ float sigf(float x) { return 1.0f / (1.0f + __expf(-x)); }
__device__ __forceinline__ float tanh_(float x) {
    float e = __expf(2.0f * x);
    return 1.0f - 2.0f / (e + 1.0f);
}
__device__ __forceinline__ float leaky(float x) { return (x > 0.0f) ? x : 0.2f * x; }
__device__ __forceinline__ u16 bhi(float v) {
    unsigned u = __float_as_uint(v);
    return (u16)((u + 0x7FFFu + ((u >> 16) & 1u)) >> 16);
}
__device__ __forceinline__ float bf2f(u16 h) { return __uint_as_float(((unsigned)h) << 16); }

// ====================== A: traj LSTM (no barriers) ========================
__global__ __launch_bounds__(256, 1)
void traj_lstm_k(const float* __restrict__ obs,
                 const float* __restrict__ h0,
                 const float* __restrict__ c0,
                 const float* __restrict__ w_ih,
                 const float* __restrict__ w_hh,
                 const float* __restrict__ b_ih,
                 const float* __restrict__ b_hh,
                 float* __restrict__ ws1,    // xn f32 [8][32][N]
                 float* __restrict__ wsT)    // raw h at t=7, [32][N]
{
    const int tid = threadIdx.x;
    const int n   = blockIdx.x * 256 + tid;
    __shared__ __attribute__((aligned(16))) float W[128 * 36];
    __shared__ float hc[256 * 33 * 2];
    float* hl = &hc[tid * 33];
    float* cl = &hc[(256 + tid) * 33];

    for (int i = tid; i < 128 * 36; i += 256) {
        int gate = i / 36, k = i - gate * 36;
        float v;
        if (k < 32)      v = w_hh[gate * 32 + k];
        else if (k < 35) v = w_ih[gate * 3 + (k - 32)];
        else             v = b_ih[gate] + b_hh[gate];
        W[i] = v;
    }
    #pragma unroll
    for (int j4 = 0; j4 < 8; ++j4) {
        f32x4 hv = *(const f32x4*)&h0[(size_t)n * 32 + j4 * 4];
        f32x4 cv = *(const f32x4*)&c0[(size_t)n * 32 + j4 * 4];
        #pragma unroll
        for (int r = 0; r < 4; ++r) { hl[j4 * 4 + r] = hv[r]; cl[j4 * 4 + r] = cv[r]; }
    }
    __syncthreads();

    for (int t = 0; t < OBS; ++t) {
        f32x4 v4[9];
        #pragma unroll
        for (int kq = 0; kq < 8; ++kq) {
            f32x4 x;
            #pragma unroll
            for (int r = 0; r < 4; ++r) x[r] = hl[kq * 4 + r];
            v4[kq] = x;
        }
        {
            const float* ob = &obs[((size_t)t * NTOT + n) * 3];
            v4[8] = (f32x4){ob[0], ob[1], ob[2], 1.0f};
        }
        #pragma unroll 4
        for (int j = 0; j < 32; ++j) {
            f32x4 ai = {0,0,0,0}, af4 = {0,0,0,0}, ag4 = {0,0,0,0}, ao4 = {0,0,0,0};
            #pragma unroll
            for (int kq = 0; kq < 9; ++kq) {
                ai  += *(const f32x4*)&W[(j)      * 36 + kq * 4] * v4[kq];
                af4 += *(const f32x4*)&W[(32 + j) * 36 + kq * 4] * v4[kq];
                ag4 += *(const f32x4*)&W[(64 + j) * 36 + kq * 4] * v4[kq];
                ao4 += *(const f32x4*)&W[(96 + j) * 36 + kq * 4] * v4[kq];
            }
            float gi = (ai[0]  + ai[1])  + (ai[2]  + ai[3]);
            float gf = (af4[0] + af4[1]) + (af4[2] + af4[3]);
            float gg = (ag4[0] + ag4[1]) + (ag4[2] + ag4[3]);
            float go = (ao4[0] + ao4[1]) + (ao4[2] + ao4[3]);
            float cc = sigf(gf) * cl[j] + sigf(gi) * tanh_(gg);
            cl[j] = cc;
            hl[j] = sigf(go) * tanh_(cc);
        }
        #pragma unroll 4
        for (int f = 0; f < 32; ++f) {
            float v = hl[f];
            float sm = v, sq = v * v;
            #pragma unroll
            for (int m = 1; m < 64; m <<= 1) { sm += __shfl_xor(sm, m); sq += __shfl_xor(sq, m); }
            float mean = sm * (1.0f / 64.0f);
            float var  = sq * (1.0f / 64.0f) - mean * mean;
            ws1[((size_t)t * 32 + f) * NTOT + n] = (v - mean) * rsqrtf(var + 1e-5f);
        }
        if (t == OBS - 1) {
            #pragma unroll 4
            for (int f = 0; f < 32; ++f) wsT[(size_t)f * NTOT + n] = hl[f];
        }
    }
}

// ====================== B: GAT, one block per (t,g) =======================
__global__ __launch_bounds__(512, 2)
void gat_k(const float* __restrict__ ws1,
           const float* __restrict__ g1w,
           const float* __restrict__ g1as,
           const float* __restrict__ g1ad,
           const float* __restrict__ g1b,
           const float* __restrict__ g2w,
           const float* __restrict__ g2as,
           const float* __restrict__ g2ad,
           const float* __restrict__ g2b,
           float* __restrict__ ws2)
{
    const int t    = blockIdx.x >> 10;
    const int g    = blockIdx.x & 1023;
    const int lane = threadIdx.x & 63;
    const int wv   = __builtin_amdgcn_readfirstlane((int)(threadIdx.x >> 6));

    __shared__ float hp1s[4096];
    __shared__ float xnx[4096];
    __shared__ float sp1s[512], dp1s[512], sp2s[512], dp2s[512];
    float* xn  = xnx;
    float* x2  = xnx;
    float* hp2 = hp1s;

    #pragma unroll
    for (int r = 0; r < 4; ++r) {
        int f = wv * 4 + r;
        xn[f * 64 + lane] = ws1[((size_t)t * 32 + f) * NTOT + g * 64 + lane];
    }
    __syncthreads();
    {
        const int h_ = wv >> 1;
        const int o0 = (wv & 1) * 8;
        float acc[8];
        #pragma unroll
        for (int q = 0; q < 8; ++q) acc[q] = 0.0f;
        for (int k8 = 0; k8 < 4; ++k8) {
            float xk[8];
            #pragma unroll
            for (int i = 0; i < 8; ++i) xk[i] = xn[(k8 * 8 + i) * 64 + lane];
            #pragma unroll
            for (int i = 0; i < 8; ++i)
                #pragma unroll
                for (int q = 0; q < 8; ++q)
                    acc[q] += g1w[h_ * 512 + (k8 * 8 + i) * 16 + o0 + q] * xk[i];
        }
        float ps = 0.0f, pd = 0.0f;
        #pragma unroll
        for (int q = 0; q < 8; ++q) {
            hp1s[(h_ * 16 + o0 + q) * 64 + lane] = acc[q];
            ps += acc[q] * g1as[h_ * 16 + o0 + q];
            pd += acc[q] * g1ad[h_ * 16 + o0 + q];
        }
        sp1s[((wv & 1) * 4 + h_) * 64 + lane] = ps;
        dp1s[((wv & 1) * 4 + h_) * 64 + lane] = pd;
    }
    __syncthreads();
    {
        const int h_ = wv >> 1;
        const int o0 = (wv & 1) * 8;
        const float sv   = sp1s[h_ * 64 + lane] + sp1s[(4 + h_) * 64 + lane];
        const float dtot = dp1s[h_ * 64 + lane] + dp1s[(4 + h_) * 64 + lane];
        float sum = 0.0f;
        float acc[8];
        #pragma unroll
        for (int q = 0; q < 8; ++q) acc[q] = 0.0f;
        #pragma unroll
        for (int m4 = 0; m4 < 16; ++m4) {
            float e0 = __expf(leaky(sv + __shfl(dtot, m4 * 4 + 0)));
            float e1 = __expf(leaky(sv + __shfl(dtot, m4 * 4 + 1)));
            float e2 = __expf(leaky(sv + __shfl(dtot, m4 * 4 + 2)));
            float e3 = __expf(leaky(sv + __shfl(dtot, m4 * 4 + 3)));
            sum += e0 + e1 + e2 + e3;
            #pragma unroll
            for (int q = 0; q < 8; ++q) {
                float4 hv = *reinterpret_cast<const float4*>(&hp1s[(h_ * 16 + o0 + q) * 64 + m4 * 4]);
                acc[q] += e0 * hv.x + e1 * hv.y + e2 * hv.z + e3 * hv.w;
            }
        }
        float rs = 1.0f / sum;
        #pragma unroll
        for (int q = 0; q < 8; ++q) {
            float v = acc[q] * rs + g1b[o0 + q];
            v = (v > 0.0f) ? v : (__expf(v) - 1.0f);
            float sm = v, sq = v * v;
            #pragma unroll
            for (int m = 1; m < 64; m <<= 1) { sm += __shfl_xor(sm, m); sq += __shfl_xor(sq, m); }
            float mean = sm * (1.0f / 64.0f);
            float var  = sq * (1.0f / 64.0f) - mean * mean;
            x2[(h_ * 16 + o0 + q) * 64 + lane] = (v - mean) * rsqrtf(var + 1e-5f);
        }
    }
    __syncthreads();
    {
        float acc[4];
        #pragma unroll
        for (int q = 0; q < 4; ++q) acc[q] = 0.0f;
        for (int k8 = 0; k8 < 8; ++k8) {
            float xk[8];
            #pragma unroll
            for (int i = 0; i < 8; ++i) xk[i] = x2[(k8 * 8 + i) * 64 + lane];
            #pragma unroll
            for (int i = 0; i < 8; ++i)
                #pragma unroll
                for (int q = 0; q < 4; ++q)
                    acc[q] += g2w[(k8 * 8 + i) * 32 + wv * 4 + q] * xk[i];
        }
        float ps = 0.0f, pd = 0.0f;
        #pragma unroll
        for (int q = 0; q < 4; ++q) {
            hp2[(wv * 4 + q) * 64 + lane] = acc[q];
            ps += acc[q] * g2as[wv * 4 + q];
            pd += acc[q] * g2ad[wv * 4 + q];
        }
        sp2s[wv * 64 + lane] = ps;
        dp2s[wv * 64 + lane] = pd;
    }
    __syncthreads();
    {
        float sv = 0.0f, dtot = 0.0f;
        #pragma unroll
        for (int w = 0; w < 8; ++w) { sv += sp2s[w * 64 + lane]; dtot += dp2s[w * 64 + lane]; }
        float sum = 0.0f;
        float acc[4];
        #pragma unroll
        for (int q = 0; q < 4; ++q) acc[q] = 0.0f;
        #pragma unroll
        for (int m4 = 0; m4 < 16; ++m4) {
            float e0 = __expf(leaky(sv + __shfl(dtot, m4 * 4 + 0)));
            float e1 = __expf(leaky(sv + __shfl(dtot, m4 * 4 + 1)));
            float e2 = __expf(leaky(sv + __shfl(dtot, m4 * 4 + 2)));
            float e3 = __expf(leaky(sv + __shfl(dtot, m4 * 4 + 3)));
            sum += e0 + e1 + e2 + e3;
            #pragma unroll
            for (int q = 0; q < 4; ++q) {
                float4 hv = *reinterpret_cast<const float4*>(&hp2[(wv * 4 + q) * 64 + m4 * 4]);
                acc[q] += e0 * hv.x + e1 * hv.y + e2 * hv.z + e3 * hv.w;
            }
        }
        float rs = 1.0f / sum;
        #pragma unroll
        for (int q = 0; q < 4; ++q)
            ws2[((size_t)t * 32 + wv * 4 + q) * NTOT + g * 64 + lane] = acc[q] * rs + g2b[wv * 4 + q];
    }
}

// ====================== C: graph LSTM (MFMA, operand-swapped) =============
__global__ __launch_bounds__(512, 1)
void graph_lstm_k(const float* __restrict__ ws2,
                  const float* __restrict__ graph_h0,
                  const float* __restrict__ graph_c0,
                  const float* __restrict__ w_ih_g,
                  const float* __restrict__ w_hh_g,
                  const float* __restrict__ b_ih_g,
                  const float* __restrict__ b_hh_g,
                  float* __restrict__ wsG)
{
    const int g    = blockIdx.x;
    const int lane = threadIdx.x & 63;
    const int wv   = __builtin_amdgcn_readfirstlane((int)(threadIdx.x >> 6));
    const int n    = g * NPED + lane;

    __shared__ __attribute__((aligned(16))) u16 AGh[64 * EAP], AGl[64 * EAP];
    __shared__ float biasg[128];

    const int pfrag = lane & 15, kg8 = (lane >> 4) * 8;
    const int pcol = lane & 15;
    const int jg   = wv * 4 + (lane >> 4);

    short8_t wfhG[2], wflG[2];
    {
        int gp = wv * 16 + pfrag, j = gp >> 2, ty = gp & 3, orig = ty * 32 + j;
        #pragma unroll
        for (int kb = 0; kb < 2; ++kb) {
            short8_t fhG, flG;
            #pragma unroll
            for (int jj = 0; jj < 8; ++jj) {
                int k = kb * 32 + (lane >> 4) * 8 + jj;
                float vG = (k < 32) ? w_ih_g[orig * 32 + k] : w_hh_g[orig * 32 + (k - 32)];
                u16 hG = bhi(vG); fhG[jj] = (short)hG; flG[jj] = (short)bhi(vG - bf2f(hG));
            }
            wfhG[kb] = fhG; wflG[kb] = flG;
        }
    }
    #pragma unroll
    for (int r = 0; r < 4; ++r) {
        int j = wv * 4 + r;
        float vg = graph_h0[(size_t)n * HG_ + j];
        u16 hg = bhi(vg);
        AGh[lane * EAP + 32 + j] = hg;  AGl[lane * EAP + 32 + j] = bhi(vg - bf2f(hg));
    }
    float cG2[4];
    #pragma unroll
    for (int mb = 0; mb < 4; ++mb)
        cG2[mb] = graph_c0[(size_t)(g * 64 + mb * 16 + pcol) * HG_ + jg];
    if (threadIdx.x < 128) biasg[threadIdx.x] = b_ih_g[threadIdx.x] + b_hh_g[threadIdx.x];

    for (int t = 0; t < OBS; ++t) {
        #pragma unroll
        for (int r = 0; r < 4; ++r) {
            int f = wv * 4 + r;
            float v = ws2[((size_t)t * 32 + f) * NTOT + g * 64 + lane];
            u16 h = bhi(v);
            AGh[lane * EAP + f] = h;  AGl[lane * EAP + f] = bhi(v - bf2f(h));
        }
        __syncthreads();   // B1
        float h2G[4];
        {
            f32x4 acc[4];
            #pragma unroll
            for (int mb = 0; mb < 4; ++mb) acc[mb] = (f32x4){0.f, 0.f, 0.f, 0.f};
            #pragma unroll
            for (int kb = 0; kb < 2; ++kb) {
                short8_t ah[4], al[4];
                #pragma unroll
                for (int mb = 0; mb < 4; ++mb) {
                    int off = (mb * 16 + pfrag) * EAP + kb * 32 + kg8;
                    ah[mb] = *(const short8_t*)&AGh[off];
                    al[mb] = *(const short8_t*)&AGl[off];
                }
                #pragma unroll
                for (int mb = 0; mb < 4; ++mb) {
                    acc[mb] = __builtin_amdgcn_mfma_f32_16x16x32_bf16(wfhG[kb], ah[mb], acc[mb], 0, 0, 0);
                    acc[mb] = __builtin_amdgcn_mfma_f32_16x16x32_bf16(wflG[kb], ah[mb], acc[mb], 0, 0, 0);
                    acc[mb] = __builtin_amdgcn_mfma_f32_16x16x32_bf16(wfhG[kb], al[mb], acc[mb], 0, 0, 0);
                }
            }
            const float bI = biasg[jg], bF = biasg[32 + jg], bG = biasg[64 + jg], bO = biasg[96 + jg];
            #pragma unroll
            for (int mb = 0; mb < 4; ++mb) {
                float gi = acc[mb][0] + bI, gf = acc[mb][1] + bF;
                float gg = acc[mb][2] + bG, go = acc[mb][3] + bO;
                float c = sigf(gf) * cG2[mb] + sigf(gi) * tanh_(gg);
                cG2[mb] = c;
                h2G[mb] = sigf(go) * tanh_(c);
            }
        }
        __syncthreads();   // B2
        #pragma unroll
        for (int mb = 0; mb < 4; ++mb) {
            int p = mb * 16 + pcol;
            u16 h = bhi(h2G[mb]);
            AGh[p * EAP + 32 + jg] = h;  AGl[p * EAP + 32 + jg] = bhi(h2G[mb] - bf2f(h));
        }
        if (t == OBS - 1) {
            #pragma unroll
            for (int mb = 0; mb < 4; ++mb)
                wsG[(size_t)jg * NTOT + g * 64 + mb * 16 + pcol] = h2G[mb];
        }
    }
}

// ============ D: decoder (balanced: 2 tiles + 1 quarter-job per wave) =====
__global__ __launch_bounds__(512, 1)
void stgat_dec(const float* __restrict__ obs,
               const float* __restrict__ zin,
               const float* __restrict__ w_ih_p,
               const float* __restrict__ w_hh_p,
               const float* __restrict__ b_ih_p,
               const float* __restrict__ b_hh_p,
               const float* __restrict__ w_out,
               const float* __restrict__ b_out,
               const float* __restrict__ wsT,
               const float* __restrict__ wsG,
               float* __restrict__ out)
{
    const int g    = blockIdx.x;
    const int lane = threadIdx.x & 63;
    const int wv   = __builtin_amdgcn_readfirstlane((int)(threadIdx.x >> 6));
    const int n    = g * NPED + lane;

    __shared__ __attribute__((aligned(16))) u16 Apk[2 * 64 * AP2 + 16]; // 20512 B (+guard)
    __shared__ __attribute__((aligned(16))) short8_t WloS[18 * 3 * 64]; // 55296 B
    __shared__ float red0[512], red1[512];                              // 4096 B
    u16* AhiA = Apk;
    u16* AhiB = Apk + 64 * AP2;

    const int pfrag = lane & 15, kgrp = (lane >> 4) * 8;
    const int pcol  = lane & 15;
    const int mb2   = wv & 3;                    // quarter-job mb (wave-uniform)
    const int nb2   = 16 + (wv >> 2);            // quarter-job tile

    // tiles owned: s=0 -> wv, s=1 -> 8+wv, s=2 -> nb2 (quarter: mb2 only)
    short8_t wfh[3][3];
    {
        const int col = lane & 15, lb = lane >> 4;
        #pragma unroll
        for (int s = 0; s < 3; ++s) {
            int nb = (s == 2) ? nb2 : (wv + 8 * s);
            int gp = nb * 16 + col;
            int j = gp >> 2, ty = gp & 3;
            int orig = ty * HP_ + j;
            #pragma unroll
            for (int kb = 0; kb < 3; ++kb) {
                short8_t fh, fl;
                #pragma unroll
                for (int jj = 0; jj < 8; ++jj) {
                    int k = kb * 32 + lb * 8 + jj;
                    float v;
                    if (k < 72)       v = w_hh_p[orig * HP_ + k];
                    else if (k == 72) v = w_ih_p[orig * 2 + 0];
                    else if (k == 73) v = w_ih_p[orig * 2 + 1];
                    else if (k == 74) v = b_ih_p[orig] + b_hh_p[orig];
                    else              v = 0.0f;
                    u16 hb = bhi(v);
                    fh[jj] = (short)hb;
                    fl[jj] = (short)bhi(v - bf2f(hb));
                }
                wfh[s][kb] = fh;
                if (s < 2 || (wv & 3) == 0)       // tiles 16,17 written once (wv 0,4)
                    WloS[(nb * 3 + kb) * 64 + lane] = fl;
            }
        }
    }
    float wo0[3], wo1[3];
    #pragma unroll
    for (int s = 0; s < 3; ++s) {
        int nb = (s == 2) ? nb2 : (wv + 8 * s);
        int j = nb * 4 + (lane >> 4);
        wo0[s] = w_out[j];
        wo1[s] = w_out[HP_ + j];
    }
    const float bo0 = b_out[0], bo1 = b_out[1];

    {
        float px0 = obs[(7 * NTOT + n) * 3 + 0];
        float px1 = obs[(7 * NTOT + n) * 3 + 1];
        #pragma unroll
        for (int kk = 0; kk < 12; ++kk) {
            int k = wv + kk * 8;
            if (k < AP2) {
                float va, vb;
                if (k < 32)       { va = wsT[(size_t)k * NTOT + n];            vb = 0.0f; }
                else if (k < 64)  { va = vb = wsG[(size_t)(k - 32) * NTOT + n]; }
                else if (k < 72)  { va = vb = zin[g * NZ_ + (k - 64)]; }
                else if (k == 72) { va = vb = px0; }
                else if (k == 73) { va = vb = px1; }
                else if (k == 74) { va = vb = 1.0f; }
                else              { va = vb = 0.0f; }
                AhiA[lane * AP2 + k] = bhi(va);
                AhiB[lane * AP2 + k] = bhi(vb);
            }
        }
        if (wv == 0 && lane < 16) Apk[2 * 64 * AP2 + lane] = 0;   // guard
    }
    __syncthreads();

    float cstA[2][4], cstB[2][4], cstA2 = 0.f, cstB2 = 0.f;
    #pragma unroll
    for (int s = 0; s < 2; ++s)
        #pragma unroll
        for (int mb = 0; mb < 4; ++mb) { cstA[s][mb] = 0.0f; cstB[s][mb] = 0.0f; }

    for (int st = 0; st < FUT; ++st) {
        float h2A[2][4], h2B[2][4], h2A2, h2B2;
        // ---- cell A ----
        {
            f32x4 acc[2][4];
            f32x4 acc2 = (f32x4){0.f, 0.f, 0.f, 0.f};
            #pragma unroll
            for (int s = 0; s < 2; ++s)
                #pragma unroll
                for (int mb = 0; mb < 4; ++mb) acc[s][mb] = (f32x4){0.f, 0.f, 0.f, 0.f};
            #pragma unroll
            for (int kb = 0; kb < 3; ++kb) {
                short8_t ah[4];
                #pragma unroll
                for (int mb = 0; mb < 4; ++mb) {
                    int off = (mb * 16 + pfrag) * AP2 + kb * 32 + kgrp;
                    ah[mb] = *(const short8_t*)&AhiA[off];
                }
                #pragma unroll
                for (int s = 0; s < 2; ++s) {
                    int nb = wv + 8 * s;
                    short8_t wl = WloS[(nb * 3 + kb) * 64 + lane];
                    #pragma unroll
                    for (int mb = 0; mb < 4; ++mb) {
                        acc[s][mb] = __builtin_amdgcn_mfma_f32_16x16x32_bf16(wfh[s][kb], ah[mb], acc[s][mb], 0, 0, 0);
                        acc[s][mb] = __builtin_amdgcn_mfma_f32_16x16x32_bf16(wl,         ah[mb], acc[s][mb], 0, 0, 0);
                    }
                }
                // quarter-job: re-read fragment at runtime-uniform mb2 (no reg-array dyn index)
                short8_t ah2 = *(const short8_t*)&AhiA[(mb2 * 16 + pfrag) * AP2 + kb * 32 + kgrp];
                short8_t wl2 = WloS[(nb2 * 3 + kb) * 64 + lane];
                acc2 = __builtin_amdgcn_mfma_f32_16x16x32_bf16(wfh[2][kb], ah2, acc2, 0, 0, 0);
                acc2 = __builtin_amdgcn_mfma_f32_16x16x32_bf16(wl2,        ah2, acc2, 0, 0, 0);
            }
            #pragma unroll
            for (int s = 0; s < 2; ++s)
                #pragma unroll
                for (int mb = 0; mb < 4; ++mb) {
                    float gi = acc[s][mb][0], gf = acc[s][mb][1];
                    float gg = acc[s][mb][2], go = acc[s][mb][3];
                    float c = sigf(gf) * cstA[s][mb] + sigf(gi) * tanh_(gg);
                    cstA[s][mb] = c;
                    h2A[s][mb] = sigf(go) * tanh_(c);
                }
            {
                float gi = acc2[0], gf = acc2[1], gg = acc2[2], go = acc2[3];
                float c = sigf(gf) * cstA2 + sigf(gi) * tanh_(gg);
                cstA2 = c;
                h2A2 = sigf(go) * tanh_(c);
            }
        }
        // ---- cell B ----
        {
            f32x4 acc[2][4];
            f32x4 acc2 = (f32x4){0.f, 0.f, 0.f, 0.f};
            #pragma unroll
            for (int s = 0; s < 2; ++s)
                #pragma unroll
                for (int mb = 0; mb < 4; ++mb) acc[s][mb] = (f32x4){0.f, 0.f, 0.f, 0.f};
            #pragma unroll
            for (int kb = 0; kb < 3; ++kb) {
                short8_t bh[4];
                #pragma unroll
                for (int mb = 0; mb < 4; ++mb) {
                    int off = (mb * 16 + pfrag) * AP2 + kb * 32 + kgrp;
                    bh[mb] = *(const short8_t*)&AhiB[off];
                }
                #pragma unroll
                for (int s = 0; s < 2; ++s) {
                    int nb = wv + 8 * s;
                    short8_t wl = WloS[(nb * 3 + kb) * 64 + lane];
                    #pragma unroll
                    for (int mb = 0; mb < 4; ++mb) {
                        acc[s][mb] = __builtin_amdgcn_mfma_f32_16x16x32_bf16(wfh[s][kb], bh[mb], acc[s][mb], 0, 0, 0);
                        acc[s][mb] = __builtin_amdgcn_mfma_f32_16x16x32_bf16(wl,         bh[mb], acc[s][mb], 0, 0, 0);
                    }
                }
                short8_t bh2 = *(const short8_t*)&AhiB[(mb2 * 16 + pfrag) * AP2 + kb * 32 + kgrp];
                short8_t wl2 = WloS[(nb2 * 3 + kb) * 64 + lane];
                acc2 = __builtin_amdgcn_mfma_f32_16x16x32_bf16(wfh[2][kb], bh2, acc2, 0, 0, 0);
                acc2 = __builtin_amdgcn_mfma_f32_16x16x32_bf16(wl2,        bh2, acc2, 0, 0, 0);
            }
            #pragma unroll
            for (int s = 0; s < 2; ++s)
                #pragma unroll
                for (int mb = 0; mb < 4; ++mb) {
                    float gi = acc[s][mb][0], gf = acc[s][mb][1];
                    float gg = acc[s][mb][2], go = acc[s][mb][3];
                    float c = sigf(gf) * cstB[s][mb] + sigf(gi) * tanh_(gg);
                    cstB[s][mb] = c;
                    h2B[s][mb] = sigf(go) * tanh_(c);
                }
            {
                float gi = acc2[0], gf = acc2[1], gg = acc2[2], go = acc2[3];
                float c = sigf(gf) * cstB2 + sigf(gi) * tanh_(gg);
                cstB2 = c;
                h2B2 = sigf(go) * tanh_(c);
            }
        }
        // ---- register partial dot (incl. quarter-job via unrolled cond add) ----
        float po0[4] = {0.f, 0.f, 0.f, 0.f}, po1[4] = {0.f, 0.f, 0.f, 0.f};
        #pragma unroll
        for (int s = 0; s < 2; ++s)
            #pragma unroll
            for (int mb = 0; mb < 4; ++mb) {
                float dh = h2A[s][mb] - h2B[s][mb];
                po0[mb] += wo0[s] * dh;
                po1[mb] += wo1[s] * dh;
            }
        {
            float dh2 = h2A2 - h2B2;
            float c0 = wo0[2] * dh2, c1 = wo1[2] * dh2;
            #pragma unroll
            for (int mb = 0; mb < 4; ++mb) {
                po0[mb] += (mb == mb2) ? c0 : 0.0f;
                po1[mb] += (mb == mb2) ? c1 : 0.0f;
            }
        }
        #pragma unroll
        for (int mb = 0; mb < 4; ++mb) {
            po0[mb] += __shfl_xor(po0[mb], 16);  po0[mb] += __shfl_xor(po0[mb], 32);
            po1[mb] += __shfl_xor(po1[mb], 16);  po1[mb] += __shfl_xor(po1[mb], 32);
        }
        __syncthreads();   // B1: all GEMM reads of Apack done
        // ---- h2 write-back (hi only) ----
        #pragma unroll
        for (int s = 0; s < 2; ++s) {
            int j = (wv + 8 * s) * 4 + (lane >> 4);
            #pragma unroll
            for (int mb = 0; mb < 4; ++mb) {
                int p = mb * 16 + pcol;
                AhiA[p * AP2 + j] = bhi(h2A[s][mb]);
                AhiB[p * AP2 + j] = bhi(h2B[s][mb]);
            }
        }
        {
            int j2 = nb2 * 4 + (lane >> 4);
            int p2 = mb2 * 16 + pcol;
            AhiA[p2 * AP2 + j2] = bhi(h2A2);
            AhiB[p2 * AP2 + j2] = bhi(h2B2);
        }
        if ((lane >> 4) == 0) {
            #pragma unroll
            for (int mb = 0; mb < 4; ++mb) {
                red0[wv * 64 + mb * 16 + lane] = po0[mb];
                red1[wv * 64 + mb * 16 + lane] = po1[mb];
            }
        }
        __syncthreads();   // B2: h2 + partials visible
        if (wv == 0) {     // lane == ped
            float o0 = bo0, o1 = bo1;
            #pragma unroll
            for (int w = 0; w < 8; ++w) { o0 += red0[w * 64 + lane]; o1 += red1[w * 64 + lane]; }
            *reinterpret_cast<float2*>(&out[(size_t)(st * NTOT + n) * 2]) = make_float2(o0, o1);
            u16 h0_ = bhi(o0);
            u16 h1  = bhi(o1);
            AhiA[lane * AP2 + 72] = h0_;  AhiB[lane * AP2 + 72] = h0_;
            AhiA[lane * AP2 + 73] = h1;   AhiB[lane * AP2 + 73] = h1;
        }
        __syncthreads();   // B3: px visible for next step
    }
}

extern "C" void kernel_launch(void* const* d_in, const int* in_sizes, int n_in,
                              void* d_out, int out_size, void* d_ws, size_t ws_size,
                              hipStream_t stream) {
    (void)in_sizes; (void)n_in; (void)out_size; (void)ws_size;
    const size_t NF = (size_t)OBS * 32 * NTOT;
    float* ws1 = (float*)d_ws;
    float* ws2 = ws1 + NF;
    float* wsT = ws2 + NF;
    float* wsG = wsT + (size_t)32 * NTOT;

    traj_lstm_k<<<dim3(NTOT / 256), dim3(256), 0, stream>>>(
        (const float*)d_in[0], (const float*)d_in[2], (const float*)d_in[3],
        (const float*)d_in[6], (const float*)d_in[7], (const float*)d_in[8], (const float*)d_in[9],
        ws1, wsT);

    gat_k<<<dim3(OBS * NGR), dim3(512), 0, stream>>>(
        ws1,
        (const float*)d_in[10], (const float*)d_in[11], (const float*)d_in[12], (const float*)d_in[13],
        (const float*)d_in[14], (const float*)d_in[15], (const float*)d_in[16], (const float*)d_in[17],
        ws2);

    graph_lstm_k<<<dim3(NGR), dim3(512), 0, stream>>>(
        ws2, (const float*)d_in[4], (const float*)d_in[5],
        (const float*)d_in[18], (const float*)d_in[19], (const float*)d_in[20], (const float*)d_in[21],
        wsG);

    stgat_dec<<<dim3(NGR), dim3(512), 0, stream>>>(
        (const float*)d_in[0], (const float*)d_in[1],
        (const float*)d_in[22], (const float*)d_in[23],
        (const float*)d_in[24], (const float*)d_in[25],
        (const float*)d_in[26], (const float*)d_in[27],
        wsT, wsG, (float*)d_out);
}